// Round 1
// baseline (4611.721 us; speedup 1.0000x reference)
//
#include <hip/hip_runtime.h>
#include <math.h>

// ---------------- model constants ----------------
#define BB 16
#define LL 2048
#define CHUNK 10
#define DD 256
#define NLAYERS 4
#define FFD 1024
#define NCLS 10
#define NFFT 4096

// ================= embed: xs = reshape(x) @ inp_w + inp_b + PE =================
__global__ __launch_bounds__(256)
void embed_k(const float* __restrict__ x, const float* __restrict__ iw,
             const float* __restrict__ ib, float* __restrict__ xs)
{
    const int tid = threadIdx.x;
    const size_t row0 = (size_t)blockIdx.x * 8;
    const int i2 = (tid >> 1) * 2;
    const float div = expf(-0.03597789207803197f * (float)i2); // ln(10000)/256
    float wcol[CHUNK];
#pragma unroll
    for (int c = 0; c < CHUNK; ++c) wcol[c] = iw[c * DD + tid];
    const float bv = ib[tid];
    for (int rr = 0; rr < 8; ++rr) {
        size_t row = row0 + rr;
        int l = (int)(row & (LL - 1));
        const float* xr = x + row * CHUNK;
        float acc = bv;
#pragma unroll
        for (int c = 0; c < CHUNK; ++c) acc += xr[c] * wcol[c];
        float sv, cv;
        sincosf((float)l * div, &sv, &cv);
        acc += (tid & 1) ? cv : sv;
        xs[row * DD + tid] = acc;
    }
}

// ================= filter MLP: hT[d][l] = (gelu(pe16 @ w1 + b1) @ w2 + b2) =================
__global__ __launch_bounds__(256)
void filt_k(const float* __restrict__ fw1, const float* __restrict__ fb1,
            const float* __restrict__ fw2, const float* __restrict__ fb2,
            float* __restrict__ hT)
{
    __shared__ float pe[16];
    __shared__ float hid[64];
    const int tid = threadIdx.x, l = blockIdx.x;
    if (tid < 16) {
        int i2 = (tid >> 1) * 2;
        float div = expf(-0.5756462732485114f * (float)i2); // ln(10000)/16
        float sv, cv;
        sincosf((float)l * div, &sv, &cv);
        pe[tid] = (tid & 1) ? cv : sv;
    }
    __syncthreads();
    if (tid < 64) {
        float a = fb1[tid];
#pragma unroll
        for (int e = 0; e < 16; ++e) a += pe[e] * fw1[e * 64 + tid];
        hid[tid] = 0.5f * a * (1.0f + erff(a * 0.70710678118f));
    }
    __syncthreads();
    float a = fb2[tid];
#pragma unroll
    for (int h = 0; h < 64; ++h) a += hid[h] * fw2[h * DD + tid];
    hT[(size_t)tid * LL + l] = a;
}

// ================= radix-4 Stockham FFT, N=4096, 256 threads =================
__device__ __forceinline__ void fft4096_r4(float* __restrict__ AR, float* __restrict__ AI,
                                           float* __restrict__ BR, float* __restrict__ BI,
                                           int tid)
{
    float *sR = AR, *sI = AI, *dR = BR, *dI = BI;
#pragma unroll
    for (int t = 0; t < 6; ++t) {
        const int sh = 2 * t;
        const int st = 1 << sh;
        __syncthreads();
#pragma unroll
        for (int j = 0; j < 4; ++j) {
            const int u = tid + (j << 8);
            const int p = u >> sh;
            const int q = u & (st - 1);
            float aR = sR[u],        aI = sI[u];
            float bR = sR[u + 1024], bI = sI[u + 1024];
            float cR = sR[u + 2048], cI = sI[u + 2048];
            float eR = sR[u + 3072], eI = sI[u + 3072];
            float apcR = aR + cR, apcI = aI + cI;
            float amcR = aR - cR, amcI = aI - cI;
            float bpdR = bR + eR, bpdI = bI + eI;
            float bmdR = bR - eR, bmdI = bI - eI;
            float ang = -1.5339807878856412e-3f * (float)(p << sh); // -2pi/4096 * idx
            float w1i, w1r;
            __sincosf(ang, &w1i, &w1r);
            float w2r = w1r * w1r - w1i * w1i, w2i = 2.0f * w1r * w1i;
            float w3r = w2r * w1r - w2i * w1i, w3i = w2r * w1i + w2i * w1r;
            const int ob = q + ((st * p) << 2);
            dR[ob] = apcR + bpdR;
            dI[ob] = apcI + bpdI;
            float x1r = amcR + bmdI, x1i = amcI - bmdR;
            dR[ob + st] = x1r * w1r - x1i * w1i;
            dI[ob + st] = x1r * w1i + x1i * w1r;
            float x2r = apcR - bpdR, x2i = apcI - bpdI;
            dR[ob + 2 * st] = x2r * w2r - x2i * w2i;
            dI[ob + 2 * st] = x2r * w2i + x2i * w2r;
            float x3r = amcR - bmdI, x3i = amcI + bmdR;
            dR[ob + 3 * st] = x3r * w3r - x3i * w3i;
            dI[ob + 3 * st] = x3r * w3i + x3i * w3r;
        }
        float* tp;
        tp = sR; sR = dR; dR = tp;
        tp = sI; sI = dI; dI = tp;
    }
    __syncthreads(); // result in AR/AI (6 stages -> back in A)
}

// ================= Hf = FFT(zero-pad(h)) per channel =================
__global__ __launch_bounds__(256)
void ffth_k(const float* __restrict__ hT, float* __restrict__ HfR, float* __restrict__ HfI)
{
    __shared__ float AR[NFFT], AI[NFFT], BR[NFFT], BI[NFFT];
    const int tid = threadIdx.x, d = blockIdx.x;
    const float* row = hT + (size_t)d * LL;
#pragma unroll
    for (int j = 0; j < 8; ++j) {
        int k = tid + (j << 8);
        AR[k] = row[k];
        AI[k] = 0.0f;
        AR[k + 2048] = 0.0f;
        AI[k + 2048] = 0.0f;
    }
    fft4096_r4(AR, AI, BR, BI, tid);
#pragma unroll
    for (int j = 0; j < 16; ++j) {
        int k = tid + (j << 8);
        HfR[(size_t)d * NFFT + k] = AR[k];
        HfI[(size_t)d * NFFT + k] = AI[k];
    }
}

// ================= fft conv: row (b,d) of x0ct -> y (in place, = yT) =================
__global__ __launch_bounds__(256)
void fftconv_k(float* __restrict__ xrow, const float* __restrict__ HfR,
               const float* __restrict__ HfI)
{
    __shared__ float AR[NFFT], AI[NFFT], BR[NFFT], BI[NFFT];
    const int tid = threadIdx.x;
    const int blk = blockIdx.x; // b*256 + d
    const int d = blk & (DD - 1);
    float* row = xrow + (size_t)blk * LL;
#pragma unroll
    for (int j = 0; j < 8; ++j) {
        int k = tid + (j << 8);
        AR[k] = row[k];
        AI[k] = 0.0f;
        AR[k + 2048] = 0.0f;
        AI[k + 2048] = 0.0f;
    }
    fft4096_r4(AR, AI, BR, BI, tid);
    const float* hr = HfR + (size_t)d * NFFT;
    const float* hi = HfI + (size_t)d * NFFT;
#pragma unroll
    for (int j = 0; j < 16; ++j) {
        int k = tid + (j << 8);
        float xr = AR[k], xi = AI[k];
        float hR = hr[k], hI = hi[k];
        AR[k] = xr * hR - xi * hI;      // conj(X*H) for inverse via fwd FFT
        AI[k] = -(xr * hI + xi * hR);
    }
    fft4096_r4(AR, AI, BR, BI, tid);
#pragma unroll
    for (int j = 0; j < 8; ++j) {
        int k = tid + (j << 8);
        row[k] = AR[k] * (1.0f / (float)NFFT);
    }
}

// ================= depthwise conv3 + transpose: proj.x0 -> x0ct(B,D,L) =================
__global__ __launch_bounds__(256)
void shortconv_k(const float* __restrict__ proj, const float* __restrict__ sw,
                 const float* __restrict__ sb, float* __restrict__ x0ct)
{
    __shared__ float tile[34][257];
    const int tid = threadIdx.x;
    const int b = blockIdx.x >> 6;
    const int l0 = (blockIdx.x & 63) << 5; // 32 l per block
    for (int r = 0; r < 34; ++r) {
        int l = l0 - 1 + r;
        tile[r][tid] = (l >= 0 && l < LL) ? proj[((size_t)(b * LL + l)) * 768 + tid] : 0.0f;
    }
    __syncthreads();
    const int dw = tid >> 5, li = tid & 31;
    for (int dd = 0; dd < 32; ++dd) {
        int d = dd * 8 + dw;
        float w0 = sw[d * 3], w1 = sw[d * 3 + 1], w2 = sw[d * 3 + 2];
        float v = sb[d] + w0 * tile[li][d] + w1 * tile[li + 1][d] + w2 * tile[li + 2][d];
        x0ct[((size_t)(b * DD + d)) * LL + l0 + li] = v;
    }
}

// ================= gate + transpose: yg(B,L,D) = yT * x1 * x2 =================
__global__ __launch_bounds__(256)
void gate_k(const float* __restrict__ yT, const float* __restrict__ proj,
            float* __restrict__ yg)
{
    __shared__ float t[64][65];
    const int tid = threadIdx.x;
    const int blk = blockIdx.x;
    const int b = blk >> 7;
    const int dt = (blk >> 5) & 3;
    const int lt = blk & 31;
    const int d0 = dt << 6, l0 = lt << 6;
    const int r0 = tid >> 6, c = tid & 63;
    for (int rr = 0; rr < 16; ++rr) {
        int dl = rr * 4 + r0;
        t[dl][c] = yT[((size_t)(b * DD + d0 + dl)) * LL + l0 + c];
    }
    __syncthreads();
    const int lid = tid & 63, lr = tid >> 6;
    for (int k = 0; k < 16; ++k) {
        int ll = k * 4 + lr;
        int l = l0 + ll;
        size_t pb = ((size_t)(b * LL + l)) * 768;
        float v = t[lid][ll];
        yg[((size_t)(b * LL + l)) * DD + d0 + lid] =
            v * proj[pb + 256 + d0 + lid] * proj[pb + 512 + d0 + lid];
    }
}

// ================= fused (LN?) + GEMM (+GELU?) (+residual?) =================
template <int K, int NCOL, bool DO_LN, bool DO_GELU, bool DO_RES>
__global__ __launch_bounds__(256)
void lngemm_k(const float* __restrict__ in, const float* __restrict__ lng,
              const float* __restrict__ lnb, const float* __restrict__ W,
              const float* __restrict__ bias, float* __restrict__ out)
{
    constexpr int R = 16;
    constexpr int C = NCOL / 256;
    __shared__ float u[R * K];
    const int tid = threadIdx.x;
    const size_t row0 = (size_t)blockIdx.x * R;

    const float4* gin = reinterpret_cast<const float4*>(in + row0 * K);
    float4* uv = reinterpret_cast<float4*>(u);
    for (int idx = tid; idx < R * K / 4; idx += 256) uv[idx] = gin[idx];
    __syncthreads();

    if constexpr (DO_LN) {
        static_assert(K == 256, "LN only for K=256");
        const int wave = tid >> 6, lane = tid & 63;
        float g0 = lng[lane], g1 = lng[lane + 64], g2 = lng[lane + 128], g3 = lng[lane + 192];
        float b0 = lnb[lane], b1 = lnb[lane + 64], b2 = lnb[lane + 128], b3 = lnb[lane + 192];
#pragma unroll
        for (int rr = 0; rr < 4; ++rr) {
            int r = wave * 4 + rr;
            float* ur = u + r * 256;
            float v0 = ur[lane], v1 = ur[lane + 64], v2 = ur[lane + 128], v3 = ur[lane + 192];
            float s = v0 + v1 + v2 + v3;
#pragma unroll
            for (int off = 32; off > 0; off >>= 1) s += __shfl_xor(s, off, 64);
            float mean = s * (1.0f / 256.0f);
            float e0 = v0 - mean, e1 = v1 - mean, e2 = v2 - mean, e3 = v3 - mean;
            float qv = e0 * e0 + e1 * e1 + e2 * e2 + e3 * e3;
#pragma unroll
            for (int off = 32; off > 0; off >>= 1) qv += __shfl_xor(qv, off, 64);
            float rstd = rsqrtf(qv * (1.0f / 256.0f) + 1e-5f);
            ur[lane] = e0 * rstd * g0 + b0;
            ur[lane + 64] = e1 * rstd * g1 + b1;
            ur[lane + 128] = e2 * rstd * g2 + b2;
            ur[lane + 192] = e3 * rstd * g3 + b3;
        }
        __syncthreads();
    }

    float acc[R][C];
#pragma unroll
    for (int c = 0; c < C; ++c) {
        float bv = bias[tid + 256 * c];
#pragma unroll
        for (int r = 0; r < R; ++r) acc[r][c] = bv;
    }

    for (int k0 = 0; k0 < K; k0 += 4) {
        float wv[4][C];
#pragma unroll
        for (int kk = 0; kk < 4; ++kk)
#pragma unroll
            for (int c = 0; c < C; ++c)
                wv[kk][c] = W[(size_t)(k0 + kk) * NCOL + tid + 256 * c];
#pragma unroll
        for (int r = 0; r < R; ++r) {
            float4 uq = *reinterpret_cast<const float4*>(&u[r * K + k0]);
#pragma unroll
            for (int c = 0; c < C; ++c)
                acc[r][c] += uq.x * wv[0][c] + uq.y * wv[1][c] + uq.z * wv[2][c] + uq.w * wv[3][c];
        }
    }

#pragma unroll
    for (int r = 0; r < R; ++r)
#pragma unroll
        for (int c = 0; c < C; ++c) {
            float v = acc[r][c];
            if constexpr (DO_GELU) v = 0.5f * v * (1.0f + erff(v * 0.70710678118f));
            size_t o = (row0 + r) * NCOL + tid + 256 * c;
            if constexpr (DO_RES) out[o] += v;
            else out[o] = v;
        }
}

// ================= mean pool (partial) =================
__global__ __launch_bounds__(256)
void pool_k(const float* __restrict__ xs, float* __restrict__ part)
{
    const int tid = threadIdx.x;
    const int b = blockIdx.x >> 4, g = blockIdx.x & 15;
    size_t base = ((size_t)b * LL + g * 128) * DD + tid;
    float s = 0.0f;
    for (int l = 0; l < 128; ++l) s += xs[base + (size_t)l * DD];
    part[(size_t)blockIdx.x * DD + tid] = s;
}

// ================= final: LN(mean) @ cls_w + cls_b =================
__global__ __launch_bounds__(256)
void final_k(const float* __restrict__ part, const float* __restrict__ ng,
             const float* __restrict__ nb, const float* __restrict__ cw,
             const float* __restrict__ cb, float* __restrict__ out)
{
    __shared__ float pl[256];
    __shared__ float red[4], red2[4];
    const int tid = threadIdx.x, b = blockIdx.x;
    float m = 0.0f;
    for (int g = 0; g < 16; ++g) m += part[((size_t)b * 16 + g) * DD + tid];
    m *= (1.0f / (float)LL);
    const int lane = tid & 63, wave = tid >> 6;
    float s = m;
#pragma unroll
    for (int off = 32; off > 0; off >>= 1) s += __shfl_xor(s, off, 64);
    if (lane == 0) red[wave] = s;
    __syncthreads();
    float mean = (red[0] + red[1] + red[2] + red[3]) * (1.0f / 256.0f);
    float dm = m - mean;
    float qv = dm * dm;
#pragma unroll
    for (int off = 32; off > 0; off >>= 1) qv += __shfl_xor(qv, off, 64);
    if (lane == 0) red2[wave] = qv;
    __syncthreads();
    float var = (red2[0] + red2[1] + red2[2] + red2[3]) * (1.0f / 256.0f);
    pl[tid] = dm * rsqrtf(var + 1e-5f) * ng[tid] + nb[tid];
    __syncthreads();
    if (tid < NCLS) {
        float a = cb[tid];
        for (int dd = 0; dd < 256; ++dd) a += pl[dd] * cw[dd * NCLS + tid];
        out[b * NCLS + tid] = a;
    }
}

// ================= launcher =================
extern "C" void kernel_launch(void* const* d_in, const int* in_sizes, int n_in,
                              void* d_out, int out_size, void* d_ws, size_t ws_size,
                              hipStream_t stream)
{
    (void)in_sizes; (void)n_in; (void)out_size; (void)ws_size;
    const float* x        = (const float*)d_in[0];
    const float* inp_w    = (const float*)d_in[1];
    const float* inp_b    = (const float*)d_in[2];
    const float* in_proj_w= (const float*)d_in[3];
    const float* in_proj_b= (const float*)d_in[4];
    const float* short_w  = (const float*)d_in[5];
    const float* short_b  = (const float*)d_in[6];
    const float* filt_w1  = (const float*)d_in[7];
    const float* filt_b1  = (const float*)d_in[8];
    const float* filt_w2  = (const float*)d_in[9];
    const float* filt_b2  = (const float*)d_in[10];
    const float* out_w    = (const float*)d_in[11];
    const float* out_b    = (const float*)d_in[12];
    const float* ln1_g    = (const float*)d_in[13];
    const float* ln1_b    = (const float*)d_in[14];
    const float* ln2_g    = (const float*)d_in[15];
    const float* ln2_b    = (const float*)d_in[16];
    const float* ffn_w1   = (const float*)d_in[17];
    const float* ffn_b1   = (const float*)d_in[18];
    const float* ffn_w2   = (const float*)d_in[19];
    const float* ffn_b2   = (const float*)d_in[20];
    const float* norm_g   = (const float*)d_in[21];
    const float* norm_b   = (const float*)d_in[22];
    const float* cls_w    = (const float*)d_in[23];
    const float* cls_b    = (const float*)d_in[24];

    float* ws = (float*)d_ws;
    float* xs   = ws;                       // 8,388,608 f (32MB)
    float* big  = ws + 8388608;             // 33,554,432 f (128MB): proj (96MB) / hid (128MB)
    float* proj = big;
    float* yg   = big + 25165824;           // last 32MB of big (proj dead cols not needed)
    float* hid  = big;
    float* x0ct = ws + 41943040;            // 8,388,608 f (32MB), also yT (in-place)
    float* hT   = ws + 50331648;            // 524,288 f (2MB)
    float* HfR  = ws + 50855936;            // 1,048,576 f (4MB)
    float* HfI  = ws + 51904512;            // 1,048,576 f (4MB)
    float* part = ws + 52953088;            // 65,536 f
    // total 53,018,624 floats = 212.1 MB

    embed_k<<<4096, 256, 0, stream>>>(x, inp_w, inp_b, xs);

    for (int i = 0; i < NLAYERS; ++i) {
        filt_k<<<LL, 256, 0, stream>>>(filt_w1 + i * 1024, filt_b1 + i * 64,
                                       filt_w2 + i * 16384, filt_b2 + i * 256, hT);
        ffth_k<<<DD, 256, 0, stream>>>(hT, HfR, HfI);
        lngemm_k<256, 768, true, false, false><<<2048, 256, 0, stream>>>(
            xs, ln1_g + i * 256, ln1_b + i * 256, in_proj_w + (size_t)i * 196608,
            in_proj_b + i * 768, proj);
        shortconv_k<<<1024, 256, 0, stream>>>(proj, short_w + i * 768, short_b + i * 256, x0ct);
        fftconv_k<<<4096, 256, 0, stream>>>(x0ct, HfR, HfI);
        gate_k<<<2048, 256, 0, stream>>>(x0ct /* = yT */, proj, yg);
        lngemm_k<256, 256, false, false, true><<<2048, 256, 0, stream>>>(
            yg, nullptr, nullptr, out_w + (size_t)i * 65536, out_b + i * 256, xs);
        lngemm_k<256, 1024, true, true, false><<<2048, 256, 0, stream>>>(
            xs, ln2_g + i * 256, ln2_b + i * 256, ffn_w1 + (size_t)i * 262144,
            ffn_b1 + i * 1024, hid);
        lngemm_k<1024, 256, false, false, true><<<2048, 256, 0, stream>>>(
            hid, nullptr, nullptr, ffn_w2 + (size_t)i * 262144, ffn_b2 + i * 256, xs);
    }

    pool_k<<<BB * 16, 256, 0, stream>>>(xs, part);
    final_k<<<BB, 256, 0, stream>>>(part, norm_g, norm_b, cls_w, cls_b, (float*)d_out);
}

// Round 2
// 1149.153 us; speedup vs baseline: 4.0131x; 4.0131x over previous
//
#include <hip/hip_runtime.h>
#include <math.h>

// ---------------- model constants ----------------
#define BB 16
#define LL 2048
#define CHUNK 10
#define DD 256
#define NLAYERS 4
#define FFD 1024
#define NCLS 10
#define NFFT 4096

typedef short bf16x8 __attribute__((ext_vector_type(8)));
typedef short s16x4 __attribute__((ext_vector_type(4)));
typedef float f32x4 __attribute__((ext_vector_type(4)));

__device__ __forceinline__ unsigned short f2bf(float f) {
    unsigned int u = __builtin_bit_cast(unsigned int, f);
    u = (u + 0x7FFF + ((u >> 16) & 1)) >> 16;
    return (unsigned short)u;
}
__device__ __forceinline__ float bf2f(unsigned short s) {
    unsigned int u = ((unsigned int)s) << 16;
    return __builtin_bit_cast(float, u);
}

#define GLL16(gsrc, ldst) \
    __builtin_amdgcn_global_load_lds((const __attribute__((address_space(1))) void*)(gsrc), \
                                     (__attribute__((address_space(3))) void*)(ldst), 16, 0, 0)

// ================= embed: xs = reshape(x) @ inp_w + inp_b + PE =================
__global__ __launch_bounds__(256)
void embed_k(const float* __restrict__ x, const float* __restrict__ iw,
             const float* __restrict__ ib, float* __restrict__ xs)
{
    const int tid = threadIdx.x;
    const size_t row0 = (size_t)blockIdx.x * 8;
    const int i2 = (tid >> 1) * 2;
    const float div = expf(-0.03597789207803197f * (float)i2);
    float wcol[CHUNK];
#pragma unroll
    for (int c = 0; c < CHUNK; ++c) wcol[c] = iw[c * DD + tid];
    const float bv = ib[tid];
    for (int rr = 0; rr < 8; ++rr) {
        size_t row = row0 + rr;
        int l = (int)(row & (LL - 1));
        const float* xr = x + row * CHUNK;
        float acc = bv;
#pragma unroll
        for (int c = 0; c < CHUNK; ++c) acc += xr[c] * wcol[c];
        float sv, cv;
        sincosf((float)l * div, &sv, &cv);
        acc += (tid & 1) ? cv : sv;
        xs[row * DD + tid] = acc;
    }
}

// ================= filter MLP -> hT[d][l] =================
__global__ __launch_bounds__(256)
void filt_k(const float* __restrict__ fw1, const float* __restrict__ fb1,
            const float* __restrict__ fw2, const float* __restrict__ fb2,
            float* __restrict__ hT)
{
    __shared__ float pe[16];
    __shared__ float hid[64];
    const int tid = threadIdx.x, l = blockIdx.x;
    if (tid < 16) {
        int i2 = (tid >> 1) * 2;
        float div = expf(-0.5756462732485114f * (float)i2);
        float sv, cv;
        sincosf((float)l * div, &sv, &cv);
        pe[tid] = (tid & 1) ? cv : sv;
    }
    __syncthreads();
    if (tid < 64) {
        float a = fb1[tid];
#pragma unroll
        for (int e = 0; e < 16; ++e) a += pe[e] * fw1[e * 64 + tid];
        hid[tid] = 0.5f * a * (1.0f + erff(a * 0.70710678118f));
    }
    __syncthreads();
    float a = fb2[tid];
#pragma unroll
    for (int h = 0; h < 64; ++h) a += hid[h] * fw2[h * DD + tid];
    hT[(size_t)tid * LL + l] = a;
}

// ================= radix-4 Stockham FFT, N=4096, 256 threads =================
__device__ __forceinline__ void fft4096_r4(float* __restrict__ AR, float* __restrict__ AI,
                                           float* __restrict__ BR, float* __restrict__ BI,
                                           int tid)
{
    float *sR = AR, *sI = AI, *dR = BR, *dI = BI;
#pragma unroll
    for (int t = 0; t < 6; ++t) {
        const int sh = 2 * t;
        const int st = 1 << sh;
        __syncthreads();
#pragma unroll
        for (int j = 0; j < 4; ++j) {
            const int u = tid + (j << 8);
            const int p = u >> sh;
            const int q = u & (st - 1);
            float aR = sR[u],        aI = sI[u];
            float bR = sR[u + 1024], bI = sI[u + 1024];
            float cR = sR[u + 2048], cI = sI[u + 2048];
            float eR = sR[u + 3072], eI = sI[u + 3072];
            float apcR = aR + cR, apcI = aI + cI;
            float amcR = aR - cR, amcI = aI - cI;
            float bpdR = bR + eR, bpdI = bI + eI;
            float bmdR = bR - eR, bmdI = bI - eI;
            float ang = -1.5339807878856412e-3f * (float)(p << sh);
            float w1i, w1r;
            __sincosf(ang, &w1i, &w1r);
            float w2r = w1r * w1r - w1i * w1i, w2i = 2.0f * w1r * w1i;
            float w3r = w2r * w1r - w2i * w1i, w3i = w2r * w1i + w2i * w1r;
            const int ob = q + ((st * p) << 2);
            dR[ob] = apcR + bpdR;
            dI[ob] = apcI + bpdI;
            float x1r = amcR + bmdI, x1i = amcI - bmdR;
            dR[ob + st] = x1r * w1r - x1i * w1i;
            dI[ob + st] = x1r * w1i + x1i * w1r;
            float x2r = apcR - bpdR, x2i = apcI - bpdI;
            dR[ob + 2 * st] = x2r * w2r - x2i * w2i;
            dI[ob + 2 * st] = x2r * w2i + x2i * w2r;
            float x3r = amcR - bmdI, x3i = amcI + bmdR;
            dR[ob + 3 * st] = x3r * w3r - x3i * w3i;
            dI[ob + 3 * st] = x3r * w3i + x3i * w3r;
        }
        float* tp;
        tp = sR; sR = dR; dR = tp;
        tp = sI; sI = dI; dI = tp;
    }
    __syncthreads();
}

// ================= Hf = FFT(zero-pad(h)) per channel =================
__global__ __launch_bounds__(256)
void ffth_k(const float* __restrict__ hT, float* __restrict__ HfR, float* __restrict__ HfI)
{
    __shared__ float AR[NFFT], AI[NFFT], BR[NFFT], BI[NFFT];
    const int tid = threadIdx.x, d = blockIdx.x;
    const float* row = hT + (size_t)d * LL;
#pragma unroll
    for (int j = 0; j < 8; ++j) {
        int k = tid + (j << 8);
        AR[k] = row[k];
        AI[k] = 0.0f;
        AR[k + 2048] = 0.0f;
        AI[k + 2048] = 0.0f;
    }
    fft4096_r4(AR, AI, BR, BI, tid);
#pragma unroll
    for (int j = 0; j < 16; ++j) {
        int k = tid + (j << 8);
        HfR[(size_t)d * NFFT + k] = AR[k];
        HfI[(size_t)d * NFFT + k] = AI[k];
    }
}

// ================= fft conv: row (b,d) of x0ct -> y (in place) =================
__global__ __launch_bounds__(256)
void fftconv_k(float* __restrict__ xrow, const float* __restrict__ HfR,
               const float* __restrict__ HfI)
{
    __shared__ float AR[NFFT], AI[NFFT], BR[NFFT], BI[NFFT];
    const int tid = threadIdx.x;
    const int blk = blockIdx.x;
    const int d = blk & (DD - 1);
    float* row = xrow + (size_t)blk * LL;
#pragma unroll
    for (int j = 0; j < 8; ++j) {
        int k = tid + (j << 8);
        AR[k] = row[k];
        AI[k] = 0.0f;
        AR[k + 2048] = 0.0f;
        AI[k + 2048] = 0.0f;
    }
    fft4096_r4(AR, AI, BR, BI, tid);
    const float* hr = HfR + (size_t)d * NFFT;
    const float* hi = HfI + (size_t)d * NFFT;
#pragma unroll
    for (int j = 0; j < 16; ++j) {
        int k = tid + (j << 8);
        float xr = AR[k], xi = AI[k];
        float hR = hr[k], hI = hi[k];
        AR[k] = xr * hR - xi * hI;
        AI[k] = -(xr * hI + xi * hR);
    }
    fft4096_r4(AR, AI, BR, BI, tid);
#pragma unroll
    for (int j = 0; j < 8; ++j) {
        int k = tid + (j << 8);
        row[k] = AR[k] * (1.0f / (float)NFFT);
    }
}

// ================= depthwise conv3 + transpose: proj.x0(bf16) -> x0ct(B,D,L) f32 =================
__global__ __launch_bounds__(256)
void shortconv_k(const unsigned short* __restrict__ proj, const float* __restrict__ sw,
                 const float* __restrict__ sb, float* __restrict__ x0ct)
{
    __shared__ float tile[34][257];
    const int tid = threadIdx.x;
    const int b = blockIdx.x >> 6;
    const int l0 = (blockIdx.x & 63) << 5;
    for (int r = 0; r < 34; ++r) {
        int l = l0 - 1 + r;
        tile[r][tid] = (l >= 0 && l < LL) ? bf2f(proj[((size_t)(b * LL + l)) * 768 + tid]) : 0.0f;
    }
    __syncthreads();
    const int dw = tid >> 5, li = tid & 31;
    for (int dd = 0; dd < 32; ++dd) {
        int d = dd * 8 + dw;
        float w0 = sw[d * 3], w1 = sw[d * 3 + 1], w2 = sw[d * 3 + 2];
        float v = sb[d] + w0 * tile[li][d] + w1 * tile[li + 1][d] + w2 * tile[li + 2][d];
        x0ct[((size_t)(b * DD + d)) * LL + l0 + li] = v;
    }
}

// ================= gate + transpose: yg(B,L,D) bf16 = yT * x1 * x2 =================
__global__ __launch_bounds__(256)
void gate_k(const float* __restrict__ yT, const unsigned short* __restrict__ proj,
            unsigned short* __restrict__ yg)
{
    __shared__ float t[64][65];
    const int tid = threadIdx.x;
    const int blk = blockIdx.x;
    const int b = blk >> 7;
    const int dt = (blk >> 5) & 3;
    const int lt = blk & 31;
    const int d0 = dt << 6, l0 = lt << 6;
    const int r0 = tid >> 6, c = tid & 63;
    for (int rr = 0; rr < 16; ++rr) {
        int dl = rr * 4 + r0;
        t[dl][c] = yT[((size_t)(b * DD + d0 + dl)) * LL + l0 + c];
    }
    __syncthreads();
    const int lid = tid & 63, lr = tid >> 6;
    for (int k = 0; k < 16; ++k) {
        int ll = k * 4 + lr;
        int l = l0 + ll;
        size_t pb = ((size_t)(b * LL + l)) * 768;
        float v = t[lid][ll];
        float x1 = bf2f(proj[pb + 256 + d0 + lid]);
        float x2 = bf2f(proj[pb + 512 + d0 + lid]);
        yg[((size_t)(b * LL + l)) * DD + d0 + lid] = f2bf(v * x1 * x2);
    }
}

// ================= LN + cast to bf16: xln = LN(xs) =================
__global__ __launch_bounds__(256)
void lncast_k(const float* __restrict__ xs, const float* __restrict__ g,
              const float* __restrict__ b, unsigned short* __restrict__ o)
{
    const int tid = threadIdx.x, lane = tid & 63, wave = tid >> 6;
    const size_t row = (size_t)blockIdx.x * 4 + wave;
    float4 v = reinterpret_cast<const float4*>(xs + row * DD)[lane];
    float s = v.x + v.y + v.z + v.w;
#pragma unroll
    for (int off = 32; off > 0; off >>= 1) s += __shfl_xor(s, off, 64);
    float mean = s * (1.0f / 256.0f);
    float e0 = v.x - mean, e1 = v.y - mean, e2 = v.z - mean, e3 = v.w - mean;
    float q = e0 * e0 + e1 * e1 + e2 * e2 + e3 * e3;
#pragma unroll
    for (int off = 32; off > 0; off >>= 1) q += __shfl_xor(q, off, 64);
    float rstd = rsqrtf(q * (1.0f / 256.0f) + 1e-5f);
    float4 gg = reinterpret_cast<const float4*>(g)[lane];
    float4 bb = reinterpret_cast<const float4*>(b)[lane];
    s16x4 r;
    r[0] = (short)f2bf(e0 * rstd * gg.x + bb.x);
    r[1] = (short)f2bf(e1 * rstd * gg.y + bb.y);
    r[2] = (short)f2bf(e2 * rstd * gg.z + bb.z);
    r[3] = (short)f2bf(e3 * rstd * gg.w + bb.w);
    *reinterpret_cast<s16x4*>(o + row * DD + lane * 4) = r;
}

// ================= weight cast + transpose: WT[n][k] bf16 from W[k][n] f32 =================
__global__ __launch_bounds__(256)
void wcastT_k(const float* __restrict__ W, unsigned short* __restrict__ WT, int K, int N)
{
    __shared__ float t[32][33];
    const int tx = threadIdx.x & 31, ty = threadIdx.x >> 5;
    const int n0 = blockIdx.x * 32, k0 = blockIdx.y * 32;
#pragma unroll
    for (int j = 0; j < 4; ++j)
        t[ty + 8 * j][tx] = W[(size_t)(k0 + ty + 8 * j) * N + n0 + tx];
    __syncthreads();
#pragma unroll
    for (int j = 0; j < 4; ++j)
        WT[(size_t)(n0 + ty + 8 * j) * K + k0 + tx] = f2bf(t[tx][ty + 8 * j]);
}

// ================= bf16 MFMA GEMM: out = A[M,K] @ WT[N,K]^T + bias =================
// MODE 0: store bf16. MODE 1: GELU then store bf16. MODE 2: += into f32 out.
template <int K, int N, int MODE>
__global__ __launch_bounds__(256)
void gemm_k(const unsigned short* __restrict__ A, const unsigned short* __restrict__ WT,
            const float* __restrict__ bias, void* __restrict__ outp)
{
    __shared__ unsigned short ldsA[8192]; // [128][64] bf16, swizzled chunks
    __shared__ unsigned short ldsB[8192];
    const int tid = threadIdx.x;
    const int lane = tid & 63, wid = tid >> 6;
    const int row0 = blockIdx.x * 128;
    const int col0 = blockIdx.y * 128;
    const int wm = (wid >> 1) * 64, wn = (wid & 1) * 64;
    const int fr = lane & 15, fg = lane >> 4;

    f32x4 acc[4][4];
#pragma unroll
    for (int n = 0; n < 4; ++n) {
        float bv = bias[col0 + wn + n * 16 + fr];
#pragma unroll
        for (int m = 0; m < 4; ++m) {
            acc[m][n][0] = bv; acc[m][n][1] = bv; acc[m][n][2] = bv; acc[m][n][3] = bv;
        }
    }

    const int srow = wid * 8 + (lane >> 3); // staging row within 32-row group
    const int sc = lane & 7;                // staging chunk

    for (int kt = 0; kt < K / 64; ++kt) {
        const int k0 = kt * 64;
#pragma unroll
        for (int it = 0; it < 4; ++it) {
            int row = it * 32 + srow;
            int cs = sc ^ (row & 7);
            const char* ga = (const char*)(A + (size_t)(row0 + row) * K + k0) + cs * 16;
            const char* gb = (const char*)(WT + (size_t)(col0 + row) * K + k0) + cs * 16;
            GLL16(ga, (char*)ldsA + it * 4096 + wid * 1024);
            GLL16(gb, (char*)ldsB + it * 4096 + wid * 1024);
        }
        __syncthreads();
#pragma unroll
        for (int ks = 0; ks < 2; ++ks) {
            bf16x8 af[4], bf[4];
#pragma unroll
            for (int m = 0; m < 4; ++m) {
                int ar = wm + m * 16 + fr;
                int slot = (ks * 4 + fg) ^ (ar & 7);
                af[m] = *reinterpret_cast<const bf16x8*>(ldsA + ar * 64 + slot * 8);
            }
#pragma unroll
            for (int n = 0; n < 4; ++n) {
                int br = wn + n * 16 + fr;
                int slot = (ks * 4 + fg) ^ (br & 7);
                bf[n] = *reinterpret_cast<const bf16x8*>(ldsB + br * 64 + slot * 8);
            }
#pragma unroll
            for (int m = 0; m < 4; ++m)
#pragma unroll
                for (int n = 0; n < 4; ++n)
                    acc[m][n] = __builtin_amdgcn_mfma_f32_16x16x32_bf16(af[m], bf[n], acc[m][n], 0, 0, 0);
        }
        __syncthreads();
    }

#pragma unroll
    for (int m = 0; m < 4; ++m) {
        int gr = row0 + wm + m * 16 + fg * 4;
#pragma unroll
        for (int n = 0; n < 4; ++n) {
            int gc = col0 + wn + n * 16 + fr;
#pragma unroll
            for (int r = 0; r < 4; ++r) {
                float v = acc[m][n][r];
                if constexpr (MODE == 1) v = 0.5f * v * (1.0f + erff(v * 0.70710678118f));
                if constexpr (MODE <= 1) {
                    ((unsigned short*)outp)[(size_t)(gr + r) * N + gc] = f2bf(v);
                } else {
                    float* o = (float*)outp + (size_t)(gr + r) * N + gc;
                    *o += v;
                }
            }
        }
    }
}

// ================= mean pool (partial) =================
__global__ __launch_bounds__(256)
void pool_k(const float* __restrict__ xs, float* __restrict__ part)
{
    const int tid = threadIdx.x;
    const int b = blockIdx.x >> 4, g = blockIdx.x & 15;
    size_t base = ((size_t)b * LL + g * 128) * DD + tid;
    float s = 0.0f;
    for (int l = 0; l < 128; ++l) s += xs[base + (size_t)l * DD];
    part[(size_t)blockIdx.x * DD + tid] = s;
}

// ================= final: LN(mean) @ cls_w + cls_b =================
__global__ __launch_bounds__(256)
void final_k(const float* __restrict__ part, const float* __restrict__ ng,
             const float* __restrict__ nb, const float* __restrict__ cw,
             const float* __restrict__ cb, float* __restrict__ out)
{
    __shared__ float pl[256];
    __shared__ float red[4], red2[4];
    const int tid = threadIdx.x, b = blockIdx.x;
    float m = 0.0f;
    for (int g = 0; g < 16; ++g) m += part[((size_t)b * 16 + g) * DD + tid];
    m *= (1.0f / (float)LL);
    const int lane = tid & 63, wave = tid >> 6;
    float s = m;
#pragma unroll
    for (int off = 32; off > 0; off >>= 1) s += __shfl_xor(s, off, 64);
    if (lane == 0) red[wave] = s;
    __syncthreads();
    float mean = (red[0] + red[1] + red[2] + red[3]) * (1.0f / 256.0f);
    float dm = m - mean;
    float qv = dm * dm;
#pragma unroll
    for (int off = 32; off > 0; off >>= 1) qv += __shfl_xor(qv, off, 64);
    if (lane == 0) red2[wave] = qv;
    __syncthreads();
    float var = (red2[0] + red2[1] + red2[2] + red2[3]) * (1.0f / 256.0f);
    pl[tid] = dm * rsqrtf(var + 1e-5f) * ng[tid] + nb[tid];
    __syncthreads();
    if (tid < NCLS) {
        float a = cb[tid];
        for (int dd = 0; dd < 256; ++dd) a += pl[dd] * cw[dd * NCLS + tid];
        out[b * NCLS + tid] = a;
    }
}

// ================= launcher =================
extern "C" void kernel_launch(void* const* d_in, const int* in_sizes, int n_in,
                              void* d_out, int out_size, void* d_ws, size_t ws_size,
                              hipStream_t stream)
{
    (void)in_sizes; (void)n_in; (void)out_size; (void)ws_size;
    const float* x        = (const float*)d_in[0];
    const float* inp_w    = (const float*)d_in[1];
    const float* inp_b    = (const float*)d_in[2];
    const float* in_proj_w= (const float*)d_in[3];
    const float* in_proj_b= (const float*)d_in[4];
    const float* short_w  = (const float*)d_in[5];
    const float* short_b  = (const float*)d_in[6];
    const float* filt_w1  = (const float*)d_in[7];
    const float* filt_b1  = (const float*)d_in[8];
    const float* filt_w2  = (const float*)d_in[9];
    const float* filt_b2  = (const float*)d_in[10];
    const float* out_w    = (const float*)d_in[11];
    const float* out_b    = (const float*)d_in[12];
    const float* ln1_g    = (const float*)d_in[13];
    const float* ln1_b    = (const float*)d_in[14];
    const float* ln2_g    = (const float*)d_in[15];
    const float* ln2_b    = (const float*)d_in[16];
    const float* ffn_w1   = (const float*)d_in[17];
    const float* ffn_b1   = (const float*)d_in[18];
    const float* ffn_w2   = (const float*)d_in[19];
    const float* ffn_b2   = (const float*)d_in[20];
    const float* norm_g   = (const float*)d_in[21];
    const float* norm_b   = (const float*)d_in[22];
    const float* cls_w    = (const float*)d_in[23];
    const float* cls_b    = (const float*)d_in[24];

    float* ws = (float*)d_ws;
    float* xs            = ws;                         // 32MB
    float* x0ct          = ws + 8388608;               // 32MB (also yT in place)
    unsigned short* xln  = (unsigned short*)(ws + 16777216);  // 16MB bf16
    unsigned short* proj = (unsigned short*)(ws + 20971520);  // big region 64MB
    unsigned short* yg   = proj + 25165824;            // 16MB bf16 (after proj's 48MB)
    unsigned short* hid  = proj;                       // 64MB bf16 (reuses proj+yg)
    float* hT            = ws + 37748736;              // 2MB
    float* HfR           = ws + 38273024;              // 4MB
    float* HfI           = ws + 39321600;              // 4MB
    float* part          = ws + 40370176;
    unsigned short* WTb  = (unsigned short*)(ws + 40435712);  // 4 layers x 786432 bf16

    // one-time (per call) weight cast+transpose to bf16 WT[N][K]
    for (int i = 0; i < NLAYERS; ++i) {
        unsigned short* wt = WTb + (size_t)i * 786432;
        wcastT_k<<<dim3(24, 8), 256, 0, stream>>>(in_proj_w + (size_t)i * 196608, wt, 256, 768);
        wcastT_k<<<dim3(8, 8), 256, 0, stream>>>(out_w + (size_t)i * 65536, wt + 196608, 256, 256);
        wcastT_k<<<dim3(32, 8), 256, 0, stream>>>(ffn_w1 + (size_t)i * 262144, wt + 262144, 256, 1024);
        wcastT_k<<<dim3(8, 32), 256, 0, stream>>>(ffn_w2 + (size_t)i * 262144, wt + 524288, 1024, 256);
    }

    embed_k<<<4096, 256, 0, stream>>>(x, inp_w, inp_b, xs);

    for (int i = 0; i < NLAYERS; ++i) {
        unsigned short* wt = WTb + (size_t)i * 786432;
        filt_k<<<LL, 256, 0, stream>>>(filt_w1 + i * 1024, filt_b1 + i * 64,
                                       filt_w2 + i * 16384, filt_b2 + i * 256, hT);
        ffth_k<<<DD, 256, 0, stream>>>(hT, HfR, HfI);
        lncast_k<<<8192, 256, 0, stream>>>(xs, ln1_g + i * 256, ln1_b + i * 256, xln);
        gemm_k<256, 768, 0><<<dim3(256, 6), 256, 0, stream>>>(xln, wt, in_proj_b + i * 768, proj);
        shortconv_k<<<1024, 256, 0, stream>>>(proj, short_w + i * 768, short_b + i * 256, x0ct);
        fftconv_k<<<4096, 256, 0, stream>>>(x0ct, HfR, HfI);
        gate_k<<<2048, 256, 0, stream>>>(x0ct, proj, yg);
        gemm_k<256, 256, 2><<<dim3(256, 2), 256, 0, stream>>>(yg, wt + 196608, out_b + i * 256, xs);
        lncast_k<<<8192, 256, 0, stream>>>(xs, ln2_g + i * 256, ln2_b + i * 256, xln);
        gemm_k<256, 1024, 1><<<dim3(256, 8), 256, 0, stream>>>(xln, wt + 262144, ffn_b1 + i * 1024, hid);
        gemm_k<1024, 256, 2><<<dim3(256, 2), 256, 0, stream>>>(hid, wt + 524288, ffn_b2 + i * 256, xs);
    }

    pool_k<<<BB * 16, 256, 0, stream>>>(xs, part);
    final_k<<<BB, 256, 0, stream>>>(part, norm_g, norm_b, cls_w, cls_b, (float*)d_out);
}

// Round 3
// 942.410 us; speedup vs baseline: 4.8935x; 1.2194x over previous
//
#include <hip/hip_runtime.h>
#include <math.h>

// ---------------- model constants ----------------
#define BB 16
#define LL 2048
#define CHUNK 10
#define DD 256
#define NLAYERS 4
#define FFD 1024
#define NCLS 10
#define HSTR 2112   // per-channel stride of Hf arrays (2049 bins + pad)

typedef short bf16x8 __attribute__((ext_vector_type(8)));
typedef short s16x4 __attribute__((ext_vector_type(4)));
typedef float f32x4 __attribute__((ext_vector_type(4)));

__device__ __forceinline__ unsigned short f2bf(float f) {
    unsigned int u = __builtin_bit_cast(unsigned int, f);
    u = (u + 0x7FFF + ((u >> 16) & 1)) >> 16;
    return (unsigned short)u;
}
__device__ __forceinline__ float bf2f(unsigned short s) {
    unsigned int u = ((unsigned int)s) << 16;
    return __builtin_bit_cast(float, u);
}
__device__ __forceinline__ int PADI(int a) { return a + (a >> 5); }

#define GLL16(gsrc, ldst) \
    __builtin_amdgcn_global_load_lds((const __attribute__((address_space(1))) void*)(gsrc), \
                                     (__attribute__((address_space(3))) void*)(ldst), 16, 0, 0)

// ================= embed =================
__global__ __launch_bounds__(256)
void embed_k(const float* __restrict__ x, const float* __restrict__ iw,
             const float* __restrict__ ib, float* __restrict__ xs)
{
    const int tid = threadIdx.x;
    const size_t row0 = (size_t)blockIdx.x * 8;
    const int i2 = (tid >> 1) * 2;
    const float div = expf(-0.03597789207803197f * (float)i2);
    float wcol[CHUNK];
#pragma unroll
    for (int c = 0; c < CHUNK; ++c) wcol[c] = iw[c * DD + tid];
    const float bv = ib[tid];
    for (int rr = 0; rr < 8; ++rr) {
        size_t row = row0 + rr;
        int l = (int)(row & (LL - 1));
        const float* xr = x + row * CHUNK;
        float acc = bv;
#pragma unroll
        for (int c = 0; c < CHUNK; ++c) acc += xr[c] * wcol[c];
        float sv, cv;
        sincosf((float)l * div, &sv, &cv);
        acc += (tid & 1) ? cv : sv;
        xs[row * DD + tid] = acc;
    }
}

// ================= filter MLP -> hT[d][l] =================
__global__ __launch_bounds__(256)
void filt_k(const float* __restrict__ fw1, const float* __restrict__ fb1,
            const float* __restrict__ fw2, const float* __restrict__ fb2,
            float* __restrict__ hT)
{
    __shared__ float pe[16];
    __shared__ float hid[64];
    const int tid = threadIdx.x, l = blockIdx.x;
    if (tid < 16) {
        int i2 = (tid >> 1) * 2;
        float div = expf(-0.5756462732485114f * (float)i2);
        float sv, cv;
        sincosf((float)l * div, &sv, &cv);
        pe[tid] = (tid & 1) ? cv : sv;
    }
    __syncthreads();
    if (tid < 64) {
        float a = fb1[tid];
#pragma unroll
        for (int e = 0; e < 16; ++e) a += pe[e] * fw1[e * 64 + tid];
        hid[tid] = 0.5f * a * (1.0f + erff(a * 0.70710678118f));
    }
    __syncthreads();
    float a = fb2[tid];
#pragma unroll
    for (int h = 0; h < 64; ++h) a += hid[h] * fw2[h * DD + tid];
    hT[(size_t)tid * LL + l] = a;
}

// ================= mixed-radix Stockham FFT, N=2048 (r2 then 5x r4), padded LDS =================
// Data starts in (XR,XI), ends in (XR,XI). All indices padded via PADI.
__device__ __forceinline__ void fft2048(float* __restrict__ XR, float* __restrict__ XI,
                                        float* __restrict__ YR, float* __restrict__ YI,
                                        int tid)
{
    // stage 0: radix-2, st=1, u in [0,1024)
    __syncthreads();
#pragma unroll
    for (int j = 0; j < 4; ++j) {
        int u = tid + (j << 8);
        float ar = XR[PADI(u)], ai = XI[PADI(u)];
        float br = XR[PADI(u + 1024)], bi = XI[PADI(u + 1024)];
        YR[PADI(2 * u)] = ar + br;
        YI[PADI(2 * u)] = ai + bi;
        float xr = ar - br, xi = ai - bi;
        float ang = -3.0679615757712823e-3f * (float)u; // -2pi/2048 * u
        float ws, wc;
        __sincosf(ang, &ws, &wc);
        YR[PADI(2 * u + 1)] = xr * wc - xi * ws;
        YI[PADI(2 * u + 1)] = xr * ws + xi * wc;
    }
    float *sR = YR, *sI = YI, *dR = XR, *dI = XI;
#pragma unroll
    for (int t = 0; t < 5; ++t) {
        const int sh = 2 * t + 1;   // st = 2,8,32,128,512
        const int st = 1 << sh;
        __syncthreads();
#pragma unroll
        for (int j = 0; j < 2; ++j) {
            const int u = tid + (j << 8);      // u in [0,512)
            const int p = u >> sh;
            const int q = u & (st - 1);
            float aR = sR[PADI(u)],        aI = sI[PADI(u)];
            float bR = sR[PADI(u + 512)],  bI = sI[PADI(u + 512)];
            float cR = sR[PADI(u + 1024)], cI = sI[PADI(u + 1024)];
            float eR = sR[PADI(u + 1536)], eI = sI[PADI(u + 1536)];
            float apcR = aR + cR, apcI = aI + cI;
            float amcR = aR - cR, amcI = aI - cI;
            float bpdR = bR + eR, bpdI = bI + eI;
            float bmdR = bR - eR, bmdI = bI - eI;
            float ang = -3.0679615757712823e-3f * (float)(p << sh); // -2pi/2048 * p*st
            float w1i, w1r;
            __sincosf(ang, &w1i, &w1r);
            float w2r = w1r * w1r - w1i * w1i, w2i = 2.0f * w1r * w1i;
            float w3r = w2r * w1r - w2i * w1i, w3i = w2r * w1i + w2i * w1r;
            const int ob = q + ((st * p) << 2);
            dR[PADI(ob)] = apcR + bpdR;
            dI[PADI(ob)] = apcI + bpdI;
            float x1r = amcR + bmdI, x1i = amcI - bmdR;
            dR[PADI(ob + st)] = x1r * w1r - x1i * w1i;
            dI[PADI(ob + st)] = x1r * w1i + x1i * w1r;
            float x2r = apcR - bpdR, x2i = apcI - bpdI;
            dR[PADI(ob + 2 * st)] = x2r * w2r - x2i * w2i;
            dI[PADI(ob + 2 * st)] = x2r * w2i + x2i * w2r;
            float x3r = amcR - bmdI, x3i = amcI + bmdR;
            dR[PADI(ob + 3 * st)] = x3r * w3r - x3i * w3i;
            dI[PADI(ob + 3 * st)] = x3r * w3i + x3i * w3r;
        }
        float* tp;
        tp = sR; sR = dR; dR = tp;
        tp = sI; sI = dI; dI = tp;
    }
    __syncthreads(); // 6 stages total -> data back in (XR,XI)
}

// ================= H = rfft_4096(zero-pad(h)), 2049 bins per channel =================
__global__ __launch_bounds__(256)
void ffth_k(const float* __restrict__ hT, float* __restrict__ HfR, float* __restrict__ HfI)
{
    __shared__ float AR[2112], AI[2112], BR[2112], BI[2112];
    const int tid = threadIdx.x, d = blockIdx.x;
    const float2* row = reinterpret_cast<const float2*>(hT + (size_t)d * LL);
#pragma unroll
    for (int j = 0; j < 4; ++j) {
        int u = tid + (j << 8);
        float2 v = row[u];               // z[u] = h[2u] + i h[2u+1]
        AR[PADI(u)] = v.x;
        AI[PADI(u)] = v.y;
        AR[PADI(u + 1024)] = 0.0f;
        AI[PADI(u + 1024)] = 0.0f;
    }
    fft2048(AR, AI, BR, BI, tid);        // Z in A
    float* hr = HfR + (size_t)d * HSTR;
    float* hi = HfI + (size_t)d * HSTR;
#pragma unroll
    for (int j = 0; j < 4; ++j) {
        int k = 1 + tid + (j << 8);      // k in [1,1024]
        int m = 2048 - k;
        float zkr = AR[PADI(k)], zki = AI[PADI(k)];
        float zmr = AR[PADI(m)], zmi = AI[PADI(m)];
        float Er = 0.5f * (zkr + zmr), Ei = 0.5f * (zki - zmi);
        float Or = 0.5f * (zki + zmi), Oi = -0.5f * (zkr - zmr);
        float ang = -1.5339807878856412e-3f * (float)k; // -pi/2048 * k
        float ts, tc;
        __sincosf(ang, &ts, &tc);
        float TOr = tc * Or - ts * Oi, TOi = tc * Oi + ts * Or;
        hr[k] = Er + TOr;  hi[k] = Ei + TOi;          // H[k]
        hr[m] = Er - TOr;  hi[m] = -(Ei - TOi);       // H[2048-k] = conj(E - T*O)
    }
    if (tid == 0) {
        float z0r = AR[PADI(0)], z0i = AI[PADI(0)];
        hr[0] = z0r + z0i;    hi[0] = 0.0f;           // H[0]
        hr[2048] = z0r - z0i; hi[2048] = 0.0f;        // H[2048]
    }
}

// ================= fft conv via rfft-2048 pack: row (b,d) in place =================
__global__ __launch_bounds__(256)
void fftconv_k(float* __restrict__ xrow, const float* __restrict__ HfR,
               const float* __restrict__ HfI)
{
    __shared__ float AR[2112], AI[2112], BR[2112], BI[2112];
    const int tid = threadIdx.x;
    const int blk = blockIdx.x;          // b*256 + d
    const int d = blk & (DD - 1);
    float2* row = reinterpret_cast<float2*>(xrow + (size_t)blk * LL);
#pragma unroll
    for (int j = 0; j < 4; ++j) {
        int u = tid + (j << 8);
        float2 v = row[u];
        AR[PADI(u)] = v.x;
        AI[PADI(u)] = v.y;
        AR[PADI(u + 1024)] = 0.0f;
        AI[PADI(u + 1024)] = 0.0f;
    }
    fft2048(AR, AI, BR, BI, tid);        // Z in A
    const float* hr = HfR + (size_t)d * HSTR;
    const float* hi = HfI + (size_t)d * HSTR;
#pragma unroll
    for (int j = 0; j < 4; ++j) {
        int k = 1 + tid + (j << 8);      // k in [1,1024]
        int m = 2048 - k;
        float zkr = AR[PADI(k)], zki = AI[PADI(k)];
        float zmr = AR[PADI(m)], zmi = AI[PADI(m)];
        // untangle: E, O; X[k] = E + T*O; X[m] = conj(E - T*O)
        float Er = 0.5f * (zkr + zmr), Ei = 0.5f * (zki - zmi);
        float Or = 0.5f * (zki + zmi), Oi = -0.5f * (zkr - zmr);
        float ang = -1.5339807878856412e-3f * (float)k; // -pi/2048 * k
        float ts, tc;
        __sincosf(ang, &ts, &tc);
        float TOr = tc * Or - ts * Oi, TOi = tc * Oi + ts * Or;
        float Xpr = Er + TOr, Xpi = Ei + TOi;     // X[k]
        float Xmr = Er - TOr, Xmi = Ei - TOi;     // conj(X[m])
        float hkr = hr[k], hki = hi[k];
        float hmr = hr[m], hmi = hi[m];
        // Y[k] = X[k]*H[k];  C = conj(Y[m]) = conj(X[m])*conj(H[m])
        float Ykr = Xpr * hkr - Xpi * hki, Yki = Xpr * hki + Xpi * hkr;
        float Cr = Xmr * hmr + Xmi * hmi, Ci = Xmi * hmr - Xmr * hmi;
        // Ey = (Yk + C)/2;  Oy = conj(T) * (Yk - C)/2
        float Pr = 0.5f * (Ykr + Cr), Pi = 0.5f * (Yki + Ci);
        float Gr = 0.5f * (Ykr - Cr), Gi = 0.5f * (Yki - Ci);
        float Qr = tc * Gr + ts * Gi, Qi = tc * Gi - ts * Gr;
        // B[k] = conj(W[k]);  B[m] = conj(W[m])
        BR[PADI(k)] = Pr - Qi;  BI[PADI(k)] = -(Pi + Qr);
        BR[PADI(m)] = Pr + Qi;  BI[PADI(m)] = Pi - Qr;
    }
    if (tid == 0) {
        float z0r = AR[PADI(0)], z0i = AI[PADI(0)];
        float X0 = z0r + z0i, X2 = z0r - z0i;
        float Y0 = X0 * hr[0];
        float Y2 = X2 * hr[2048];
        float P = 0.5f * (Y0 + Y2), Q = 0.5f * (Y0 - Y2);
        BR[PADI(0)] = P;  BI[PADI(0)] = -Q;
    }
    fft2048(BR, BI, AR, AI, tid);        // w~ = FFT(conj(W)) in B
    const float s = 1.0f / 2048.0f;
#pragma unroll
    for (int j = 0; j < 4; ++j) {
        int u = tid + (j << 8);          // only first 1024 complex = first 2048 real samples
        float2 o;
        o.x = BR[PADI(u)] * s;
        o.y = -BI[PADI(u)] * s;
        row[u] = o;
    }
}

// ================= depthwise conv3 + transpose: proj.x0(bf16) -> x0ct(B,D,L) f32 =================
__global__ __launch_bounds__(256)
void shortconv_k(const unsigned short* __restrict__ proj, const float* __restrict__ sw,
                 const float* __restrict__ sb, float* __restrict__ x0ct)
{
    __shared__ float tile[34][257];
    const int tid = threadIdx.x;
    const int b = blockIdx.x >> 6;
    const int l0 = (blockIdx.x & 63) << 5;
    for (int r = 0; r < 34; ++r) {
        int l = l0 - 1 + r;
        tile[r][tid] = (l >= 0 && l < LL) ? bf2f(proj[((size_t)(b * LL + l)) * 768 + tid]) : 0.0f;
    }
    __syncthreads();
    const int dw = tid >> 5, li = tid & 31;
    for (int dd = 0; dd < 32; ++dd) {
        int d = dd * 8 + dw;
        float w0 = sw[d * 3], w1 = sw[d * 3 + 1], w2 = sw[d * 3 + 2];
        float v = sb[d] + w0 * tile[li][d] + w1 * tile[li + 1][d] + w2 * tile[li + 2][d];
        x0ct[((size_t)(b * DD + d)) * LL + l0 + li] = v;
    }
}

// ================= gate + transpose: yg(B,L,D) bf16 = yT * x1 * x2 =================
__global__ __launch_bounds__(256)
void gate_k(const float* __restrict__ yT, const unsigned short* __restrict__ proj,
            unsigned short* __restrict__ yg)
{
    __shared__ float t[64][65];
    const int tid = threadIdx.x;
    const int blk = blockIdx.x;
    const int b = blk >> 7;
    const int dt = (blk >> 5) & 3;
    const int lt = blk & 31;
    const int d0 = dt << 6, l0 = lt << 6;
    const int r0 = tid >> 6, c = tid & 63;
    for (int rr = 0; rr < 16; ++rr) {
        int dl = rr * 4 + r0;
        t[dl][c] = yT[((size_t)(b * DD + d0 + dl)) * LL + l0 + c];
    }
    __syncthreads();
    const int lid = tid & 63, lr = tid >> 6;
    for (int k = 0; k < 16; ++k) {
        int ll = k * 4 + lr;
        int l = l0 + ll;
        size_t pb = ((size_t)(b * LL + l)) * 768;
        float v = t[lid][ll];
        float x1 = bf2f(proj[pb + 256 + d0 + lid]);
        float x2 = bf2f(proj[pb + 512 + d0 + lid]);
        yg[((size_t)(b * LL + l)) * DD + d0 + lid] = f2bf(v * x1 * x2);
    }
}

// ================= LN + cast to bf16 =================
__global__ __launch_bounds__(256)
void lncast_k(const float* __restrict__ xs, const float* __restrict__ g,
              const float* __restrict__ b, unsigned short* __restrict__ o)
{
    const int tid = threadIdx.x, lane = tid & 63, wave = tid >> 6;
    const size_t row = (size_t)blockIdx.x * 4 + wave;
    float4 v = reinterpret_cast<const float4*>(xs + row * DD)[lane];
    float s = v.x + v.y + v.z + v.w;
#pragma unroll
    for (int off = 32; off > 0; off >>= 1) s += __shfl_xor(s, off, 64);
    float mean = s * (1.0f / 256.0f);
    float e0 = v.x - mean, e1 = v.y - mean, e2 = v.z - mean, e3 = v.w - mean;
    float q = e0 * e0 + e1 * e1 + e2 * e2 + e3 * e3;
#pragma unroll
    for (int off = 32; off > 0; off >>= 1) q += __shfl_xor(q, off, 64);
    float rstd = rsqrtf(q * (1.0f / 256.0f) + 1e-5f);
    float4 gg = reinterpret_cast<const float4*>(g)[lane];
    float4 bb = reinterpret_cast<const float4*>(b)[lane];
    s16x4 r;
    r[0] = (short)f2bf(e0 * rstd * gg.x + bb.x);
    r[1] = (short)f2bf(e1 * rstd * gg.y + bb.y);
    r[2] = (short)f2bf(e2 * rstd * gg.z + bb.z);
    r[3] = (short)f2bf(e3 * rstd * gg.w + bb.w);
    *reinterpret_cast<s16x4*>(o + row * DD + lane * 4) = r;
}

// ================= weight cast + transpose =================
__global__ __launch_bounds__(256)
void wcastT_k(const float* __restrict__ W, unsigned short* __restrict__ WT, int K, int N)
{
    __shared__ float t[32][33];
    const int tx = threadIdx.x & 31, ty = threadIdx.x >> 5;
    const int n0 = blockIdx.x * 32, k0 = blockIdx.y * 32;
#pragma unroll
    for (int j = 0; j < 4; ++j)
        t[ty + 8 * j][tx] = W[(size_t)(k0 + ty + 8 * j) * N + n0 + tx];
    __syncthreads();
#pragma unroll
    for (int j = 0; j < 4; ++j)
        WT[(size_t)(n0 + ty + 8 * j) * K + k0 + tx] = f2bf(t[tx][ty + 8 * j]);
}

// ================= bf16 MFMA GEMM =================
template <int K, int N, int MODE>
__global__ __launch_bounds__(256)
void gemm_k(const unsigned short* __restrict__ A, const unsigned short* __restrict__ WT,
            const float* __restrict__ bias, void* __restrict__ outp)
{
    __shared__ unsigned short ldsA[8192];
    __shared__ unsigned short ldsB[8192];
    const int tid = threadIdx.x;
    const int lane = tid & 63, wid = tid >> 6;
    const int row0 = blockIdx.x * 128;
    const int col0 = blockIdx.y * 128;
    const int wm = (wid >> 1) * 64, wn = (wid & 1) * 64;
    const int fr = lane & 15, fg = lane >> 4;

    f32x4 acc[4][4];
#pragma unroll
    for (int n = 0; n < 4; ++n) {
        float bv = bias[col0 + wn + n * 16 + fr];
#pragma unroll
        for (int m = 0; m < 4; ++m) {
            acc[m][n][0] = bv; acc[m][n][1] = bv; acc[m][n][2] = bv; acc[m][n][3] = bv;
        }
    }

    const int srow = wid * 8 + (lane >> 3);
    const int sc = lane & 7;

    for (int kt = 0; kt < K / 64; ++kt) {
        const int k0 = kt * 64;
#pragma unroll
        for (int it = 0; it < 4; ++it) {
            int row = it * 32 + srow;
            int cs = sc ^ (row & 7);
            const char* ga = (const char*)(A + (size_t)(row0 + row) * K + k0) + cs * 16;
            const char* gb = (const char*)(WT + (size_t)(col0 + row) * K + k0) + cs * 16;
            GLL16(ga, (char*)ldsA + it * 4096 + wid * 1024);
            GLL16(gb, (char*)ldsB + it * 4096 + wid * 1024);
        }
        __syncthreads();
#pragma unroll
        for (int ks = 0; ks < 2; ++ks) {
            bf16x8 af[4], bf[4];
#pragma unroll
            for (int m = 0; m < 4; ++m) {
                int ar = wm + m * 16 + fr;
                int slot = (ks * 4 + fg) ^ (ar & 7);
                af[m] = *reinterpret_cast<const bf16x8*>(ldsA + ar * 64 + slot * 8);
            }
#pragma unroll
            for (int n = 0; n < 4; ++n) {
                int br = wn + n * 16 + fr;
                int slot = (ks * 4 + fg) ^ (br & 7);
                bf[n] = *reinterpret_cast<const bf16x8*>(ldsB + br * 64 + slot * 8);
            }
#pragma unroll
            for (int m = 0; m < 4; ++m)
#pragma unroll
                for (int n = 0; n < 4; ++n)
                    acc[m][n] = __builtin_amdgcn_mfma_f32_16x16x32_bf16(af[m], bf[n], acc[m][n], 0, 0, 0);
        }
        __syncthreads();
    }

#pragma unroll
    for (int m = 0; m < 4; ++m) {
        int gr = row0 + wm + m * 16 + fg * 4;
#pragma unroll
        for (int n = 0; n < 4; ++n) {
            int gc = col0 + wn + n * 16 + fr;
#pragma unroll
            for (int r = 0; r < 4; ++r) {
                float v = acc[m][n][r];
                if constexpr (MODE == 1) v = 0.5f * v * (1.0f + erff(v * 0.70710678118f));
                if constexpr (MODE <= 1) {
                    ((unsigned short*)outp)[(size_t)(gr + r) * N + gc] = f2bf(v);
                } else {
                    float* o = (float*)outp + (size_t)(gr + r) * N + gc;
                    *o += v;
                }
            }
        }
    }
}

// ================= mean pool (partial) =================
__global__ __launch_bounds__(256)
void pool_k(const float* __restrict__ xs, float* __restrict__ part)
{
    const int tid = threadIdx.x;
    const int b = blockIdx.x >> 4, g = blockIdx.x & 15;
    size_t base = ((size_t)b * LL + g * 128) * DD + tid;
    float s = 0.0f;
    for (int l = 0; l < 128; ++l) s += xs[base + (size_t)l * DD];
    part[(size_t)blockIdx.x * DD + tid] = s;
}

// ================= final =================
__global__ __launch_bounds__(256)
void final_k(const float* __restrict__ part, const float* __restrict__ ng,
             const float* __restrict__ nb, const float* __restrict__ cw,
             const float* __restrict__ cb, float* __restrict__ out)
{
    __shared__ float pl[256];
    __shared__ float red[4], red2[4];
    const int tid = threadIdx.x, b = blockIdx.x;
    float m = 0.0f;
    for (int g = 0; g < 16; ++g) m += part[((size_t)b * 16 + g) * DD + tid];
    m *= (1.0f / (float)LL);
    const int lane = tid & 63, wave = tid >> 6;
    float s = m;
#pragma unroll
    for (int off = 32; off > 0; off >>= 1) s += __shfl_xor(s, off, 64);
    if (lane == 0) red[wave] = s;
    __syncthreads();
    float mean = (red[0] + red[1] + red[2] + red[3]) * (1.0f / 256.0f);
    float dm = m - mean;
    float qv = dm * dm;
#pragma unroll
    for (int off = 32; off > 0; off >>= 1) qv += __shfl_xor(qv, off, 64);
    if (lane == 0) red2[wave] = qv;
    __syncthreads();
    float var = (red2[0] + red2[1] + red2[2] + red2[3]) * (1.0f / 256.0f);
    pl[tid] = dm * rsqrtf(var + 1e-5f) * ng[tid] + nb[tid];
    __syncthreads();
    if (tid < NCLS) {
        float a = cb[tid];
        for (int dd = 0; dd < 256; ++dd) a += pl[dd] * cw[dd * NCLS + tid];
        out[b * NCLS + tid] = a;
    }
}

// ================= launcher =================
extern "C" void kernel_launch(void* const* d_in, const int* in_sizes, int n_in,
                              void* d_out, int out_size, void* d_ws, size_t ws_size,
                              hipStream_t stream)
{
    (void)in_sizes; (void)n_in; (void)out_size; (void)ws_size;
    const float* x        = (const float*)d_in[0];
    const float* inp_w    = (const float*)d_in[1];
    const float* inp_b    = (const float*)d_in[2];
    const float* in_proj_w= (const float*)d_in[3];
    const float* in_proj_b= (const float*)d_in[4];
    const float* short_w  = (const float*)d_in[5];
    const float* short_b  = (const float*)d_in[6];
    const float* filt_w1  = (const float*)d_in[7];
    const float* filt_b1  = (const float*)d_in[8];
    const float* filt_w2  = (const float*)d_in[9];
    const float* filt_b2  = (const float*)d_in[10];
    const float* out_w    = (const float*)d_in[11];
    const float* out_b    = (const float*)d_in[12];
    const float* ln1_g    = (const float*)d_in[13];
    const float* ln1_b    = (const float*)d_in[14];
    const float* ln2_g    = (const float*)d_in[15];
    const float* ln2_b    = (const float*)d_in[16];
    const float* ffn_w1   = (const float*)d_in[17];
    const float* ffn_b1   = (const float*)d_in[18];
    const float* ffn_w2   = (const float*)d_in[19];
    const float* ffn_b2   = (const float*)d_in[20];
    const float* norm_g   = (const float*)d_in[21];
    const float* norm_b   = (const float*)d_in[22];
    const float* cls_w    = (const float*)d_in[23];
    const float* cls_b    = (const float*)d_in[24];

    float* ws = (float*)d_ws;
    float* xs            = ws;                                 // 32MB f32
    float* x0ct          = ws + 8388608;                       // 32MB f32 (also yT)
    unsigned short* xln  = (unsigned short*)(ws + 16777216);   // 16MB bf16
    unsigned short* proj = (unsigned short*)(ws + 20971520);   // 48MB bf16
    unsigned short* yg   = proj + 25165824;                    // 16MB bf16
    unsigned short* hid  = proj;                               // 64MB bf16 (reuse proj+yg)
    float* hT            = ws + 37748736;                      // 2MB
    float* HfR           = ws + 38273024;                      // 256*2112 f
    float* HfI           = ws + 38813696;                      // 256*2112 f
    float* part          = ws + 39354368;
    unsigned short* WTb  = (unsigned short*)(ws + 39419904);   // 4 x 786432 bf16

    for (int i = 0; i < NLAYERS; ++i) {
        unsigned short* wt = WTb + (size_t)i * 786432;
        wcastT_k<<<dim3(24, 8), 256, 0, stream>>>(in_proj_w + (size_t)i * 196608, wt, 256, 768);
        wcastT_k<<<dim3(8, 8), 256, 0, stream>>>(out_w + (size_t)i * 65536, wt + 196608, 256, 256);
        wcastT_k<<<dim3(32, 8), 256, 0, stream>>>(ffn_w1 + (size_t)i * 262144, wt + 262144, 256, 1024);
        wcastT_k<<<dim3(8, 32), 256, 0, stream>>>(ffn_w2 + (size_t)i * 262144, wt + 524288, 1024, 256);
    }

    embed_k<<<4096, 256, 0, stream>>>(x, inp_w, inp_b, xs);

    for (int i = 0; i < NLAYERS; ++i) {
        unsigned short* wt = WTb + (size_t)i * 786432;
        filt_k<<<LL, 256, 0, stream>>>(filt_w1 + i * 1024, filt_b1 + i * 64,
                                       filt_w2 + i * 16384, filt_b2 + i * 256, hT);
        ffth_k<<<DD, 256, 0, stream>>>(hT, HfR, HfI);
        lncast_k<<<8192, 256, 0, stream>>>(xs, ln1_g + i * 256, ln1_b + i * 256, xln);
        gemm_k<256, 768, 0><<<dim3(256, 6), 256, 0, stream>>>(xln, wt, in_proj_b + i * 768, proj);
        shortconv_k<<<1024, 256, 0, stream>>>(proj, short_w + i * 768, short_b + i * 256, x0ct);
        fftconv_k<<<4096, 256, 0, stream>>>(x0ct, HfR, HfI);
        gate_k<<<2048, 256, 0, stream>>>(x0ct, proj, yg);
        gemm_k<256, 256, 2><<<dim3(256, 2), 256, 0, stream>>>(yg, wt + 196608, out_b + i * 256, xs);
        lncast_k<<<8192, 256, 0, stream>>>(xs, ln2_g + i * 256, ln2_b + i * 256, xln);
        gemm_k<256, 1024, 1><<<dim3(256, 8), 256, 0, stream>>>(xln, wt + 262144, ffn_b1 + i * 1024, hid);
        gemm_k<1024, 256, 2><<<dim3(256, 2), 256, 0, stream>>>(hid, wt + 524288, ffn_b2 + i * 256, xs);
    }

    pool_k<<<BB * 16, 256, 0, stream>>>(xs, part);
    final_k<<<BB, 256, 0, stream>>>(part, norm_g, norm_b, cls_w, cls_b, (float*)d_out);
}

// Round 4
// 883.915 us; speedup vs baseline: 5.2174x; 1.0662x over previous
//
#include <hip/hip_runtime.h>
#include <math.h>

// ---------------- model constants ----------------
#define BB 16
#define LL 2048
#define CHUNK 10
#define DD 256
#define NLAYERS 4
#define FFD 1024
#define NCLS 10
#define HSTRC 2056  // float2 stride per channel of Hf (2049 bins + pad)

typedef short bf16x8 __attribute__((ext_vector_type(8)));
typedef short s16x4 __attribute__((ext_vector_type(4)));
typedef float f32x4 __attribute__((ext_vector_type(4)));

__device__ __forceinline__ unsigned short f2bf(float f) {
    unsigned int u = __builtin_bit_cast(unsigned int, f);
    u = (u + 0x7FFF + ((u >> 16) & 1)) >> 16;
    return (unsigned short)u;
}
__device__ __forceinline__ float bf2f(unsigned short s) {
    unsigned int u = ((unsigned int)s) << 16;
    return __builtin_bit_cast(float, u);
}
__device__ __forceinline__ float bfLO(unsigned v) { return __builtin_bit_cast(float, v << 16); }
__device__ __forceinline__ float bfHI(unsigned v) { return __builtin_bit_cast(float, v & 0xFFFF0000u); }

#define PADC(a) ((a) + ((a) >> 4))

__device__ __forceinline__ float2 cmulf(float2 a, float2 b) {
    return make_float2(fmaf(-a.y, b.y, a.x * b.x), fmaf(a.y, b.x, a.x * b.y));
}

#define GLL16(gsrc, ldst) \
    __builtin_amdgcn_global_load_lds((const __attribute__((address_space(1))) void*)(gsrc), \
                                     (__attribute__((address_space(3))) void*)(ldst), 16, 0, 0)

// ================= embed =================
__global__ __launch_bounds__(256)
void embed_k(const float* __restrict__ x, const float* __restrict__ iw,
             const float* __restrict__ ib, float* __restrict__ xs)
{
    const int tid = threadIdx.x;
    const size_t row0 = (size_t)blockIdx.x * 8;
    const int i2 = (tid >> 1) * 2;
    const float div = expf(-0.03597789207803197f * (float)i2);
    float wcol[CHUNK];
#pragma unroll
    for (int c = 0; c < CHUNK; ++c) wcol[c] = iw[c * DD + tid];
    const float bv = ib[tid];
    for (int rr = 0; rr < 8; ++rr) {
        size_t row = row0 + rr;
        int l = (int)(row & (LL - 1));
        const float* xr = x + row * CHUNK;
        float acc = bv;
#pragma unroll
        for (int c = 0; c < CHUNK; ++c) acc += xr[c] * wcol[c];
        float sv, cv;
        sincosf((float)l * div, &sv, &cv);
        acc += (tid & 1) ? cv : sv;
        xs[row * DD + tid] = acc;
    }
}

// ================= filter MLP -> hT[d][l] =================
__global__ __launch_bounds__(256)
void filt_k(const float* __restrict__ fw1, const float* __restrict__ fb1,
            const float* __restrict__ fw2, const float* __restrict__ fb2,
            float* __restrict__ hT)
{
    __shared__ float pe[16];
    __shared__ float hid[64];
    const int tid = threadIdx.x, l = blockIdx.x;
    if (tid < 16) {
        int i2 = (tid >> 1) * 2;
        float div = expf(-0.5756462732485114f * (float)i2);
        float sv, cv;
        sincosf((float)l * div, &sv, &cv);
        pe[tid] = (tid & 1) ? cv : sv;
    }
    __syncthreads();
    if (tid < 64) {
        float a = fb1[tid];
#pragma unroll
        for (int e = 0; e < 16; ++e) a += pe[e] * fw1[e * 64 + tid];
        hid[tid] = 0.5f * a * (1.0f + erff(a * 0.70710678118f));
    }
    __syncthreads();
    float a = fb2[tid];
#pragma unroll
    for (int h = 0; h < 64; ++h) a += hid[h] * fw2[h * DD + tid];
    hT[(size_t)tid * LL + l] = a;
}

// ================= radix-8 Stockham FFT core, N=2048 = 8*8*8*4, float2 LDS =================
__device__ __forceinline__ void dft4c(float2 a, float2 b, float2 c, float2 d,
                                      float2& F0, float2& F1, float2& F2, float2& F3)
{
    float t0r = a.x + c.x, t0i = a.y + c.y;
    float t1r = a.x - c.x, t1i = a.y - c.y;
    float t2r = b.x + d.x, t2i = b.y + d.y;
    float t3r = b.x - d.x, t3i = b.y - d.y;
    F0 = make_float2(t0r + t2r, t0i + t2i);
    F2 = make_float2(t0r - t2r, t0i - t2i);
    F1 = make_float2(t1r + t3i, t1i - t3r);   // t1 - i*t3
    F3 = make_float2(t1r - t3i, t1i + t3r);   // t1 + i*t3
}

template <int SH>
__device__ __forceinline__ void stage8(const float2* __restrict__ src,
                                       float2* __restrict__ dst, int tid)
{
    constexpr int ST = 1 << SH;
    __syncthreads();
    const int p = tid >> SH;
    const int q = tid & (ST - 1);
    float2 x0 = src[PADC(tid)];
    float2 x1 = src[PADC(tid + 256)];
    float2 x2 = src[PADC(tid + 512)];
    float2 x3 = src[PADC(tid + 768)];
    float2 x4 = src[PADC(tid + 1024)];
    float2 x5 = src[PADC(tid + 1280)];
    float2 x6 = src[PADC(tid + 1536)];
    float2 x7 = src[PADC(tid + 1792)];
    float2 E0, E1, E2, E3, O0, O1, O2, O3;
    dft4c(x0, x2, x4, x6, E0, E1, E2, E3);
    dft4c(x1, x3, x5, x7, O0, O1, O2, O3);
    const float C8 = 0.70710678118654752f;
    float2 y0 = make_float2(E0.x + O0.x, E0.y + O0.y);
    float2 y4 = make_float2(E0.x - O0.x, E0.y - O0.y);
    float a1 = C8 * (O1.x + O1.y), b1 = C8 * (O1.y - O1.x);       // w8^1 * O1
    float2 y1 = make_float2(E1.x + a1, E1.y + b1);
    float2 y5 = make_float2(E1.x - a1, E1.y - b1);
    float2 y2 = make_float2(E2.x + O2.y, E2.y - O2.x);            // -i * O2
    float2 y6 = make_float2(E2.x - O2.y, E2.y + O2.x);
    float a3 = -C8 * (O3.x - O3.y), b3 = -C8 * (O3.x + O3.y);     // w8^3 * O3
    float2 y3 = make_float2(E3.x + a3, E3.y + b3);
    float2 y7 = make_float2(E3.x - a3, E3.y - b3);
    const int k0 = p << SH;
    float s1, c1;
    __sincosf(-3.0679615757712823e-3f * (float)k0, &s1, &c1);     // -2pi/2048 * k0
    float2 w1 = make_float2(c1, s1);
    float2 w2 = cmulf(w1, w1);
    float2 w3 = cmulf(w2, w1);
    float2 w4 = cmulf(w2, w2);
    float2 w5 = cmulf(w3, w2);
    float2 w6 = cmulf(w3, w3);
    float2 w7 = cmulf(w4, w3);
    const int ob = q + ((ST * p) << 3);
    dst[PADC(ob)] = y0;
    dst[PADC(ob + ST)] = cmulf(w1, y1);
    dst[PADC(ob + 2 * ST)] = cmulf(w2, y2);
    dst[PADC(ob + 3 * ST)] = cmulf(w3, y3);
    dst[PADC(ob + 4 * ST)] = cmulf(w4, y4);
    dst[PADC(ob + 5 * ST)] = cmulf(w5, y5);
    dst[PADC(ob + 6 * ST)] = cmulf(w6, y6);
    dst[PADC(ob + 7 * ST)] = cmulf(w7, y7);
}

// final radix-4 stage, st=512, twiddle-free (p=0)
__device__ __forceinline__ void stage4f(const float2* __restrict__ src,
                                        float2* __restrict__ dst, int tid)
{
    __syncthreads();
#pragma unroll
    for (int jj = 0; jj < 2; ++jj) {
        int u = tid + (jj << 8);
        float2 a = src[PADC(u)], b = src[PADC(u + 512)];
        float2 c = src[PADC(u + 1024)], d = src[PADC(u + 1536)];
        float2 F0, F1, F2, F3;
        dft4c(a, b, c, d, F0, F1, F2, F3);
        dst[PADC(u)] = F0;
        dst[PADC(u + 512)] = F1;
        dst[PADC(u + 1024)] = F2;
        dst[PADC(u + 1536)] = F3;
    }
}

// full FFT: data in A -> result in A (A->B->A->B->A), trailing barrier included
__device__ __forceinline__ void fft2048c(float2* __restrict__ A, float2* __restrict__ B, int tid)
{
    stage8<0>(A, B, tid);
    stage8<3>(B, A, tid);
    stage8<6>(A, B, tid);
    stage4f(B, A, tid);
    __syncthreads();
}

// ================= Hf = rfft_4096(zero-pad(h)) per channel, interleaved =================
__global__ __launch_bounds__(256)
void ffth_k(const float* __restrict__ hT, float2* __restrict__ Hf)
{
    __shared__ float2 A2[2176], B2[2176];
    const int tid = threadIdx.x, d = blockIdx.x;
    const float2* rowf = reinterpret_cast<const float2*>(hT + (size_t)d * LL);
#pragma unroll
    for (int j = 0; j < 4; ++j) {
        int u = tid + (j << 8);
        A2[PADC(u)] = rowf[u];                      // z[u] = h[2u] + i h[2u+1]
        A2[PADC(u + 1024)] = make_float2(0.0f, 0.0f);
    }
    fft2048c(A2, B2, tid);
    float2* hf = Hf + (size_t)d * HSTRC;
#pragma unroll
    for (int j = 0; j < 4; ++j) {
        int k = 1 + tid + (j << 8);                 // k in [1,1024]
        int m = 2048 - k;
        float2 zk = A2[PADC(k)], zm = A2[PADC(m)];
        float Er = 0.5f * (zk.x + zm.x), Ei = 0.5f * (zk.y - zm.y);
        float Or = 0.5f * (zk.y + zm.y), Oi = -0.5f * (zk.x - zm.x);
        float ts, tc;
        __sincosf(-1.5339807878856412e-3f * (float)k, &ts, &tc);  // -2pi/4096 * k
        float TOr = tc * Or - ts * Oi, TOi = tc * Oi + ts * Or;
        hf[k] = make_float2(Er + TOr, Ei + TOi);                  // H[k]
        hf[m] = make_float2(Er - TOr, -(Ei - TOi));               // H[2048-k]
    }
    if (tid == 0) {
        float2 z0 = A2[PADC(0)];
        hf[0] = make_float2(z0.x + z0.y, z0.x - z0.y);            // (H[0], H[2048])
    }
}

// ================= fused conv3 + fft conv: x0T(bf16) row -> yT(bf16) row =================
__global__ __launch_bounds__(256, 4)
void fftconv_k(const unsigned short* __restrict__ x0T, unsigned short* __restrict__ yT,
               const float2* __restrict__ Hf, const float* __restrict__ sw,
               const float* __restrict__ sb)
{
    __shared__ float2 A2[2176], B2[2176];
    const int tid = threadIdx.x;
    const int blk = blockIdx.x;                     // b*256 + d
    const int d = blk & (DD - 1);
    const float w0 = sw[d * 3], w1 = sw[d * 3 + 1], w2 = sw[d * 3 + 2];
    const float bv = sb[d];

    // ---- load raw bf16 row into LDS floats (B2 as scratch) ----
    float* rawF = reinterpret_cast<float*>(B2);
    {
        const uint4* rowv = reinterpret_cast<const uint4*>(x0T + (size_t)blk * LL);
        uint4 ld = rowv[tid];
        float4* dst = reinterpret_cast<float4*>(rawF + 8 * tid);
        dst[0] = make_float4(bfLO(ld.x), bfHI(ld.x), bfLO(ld.y), bfHI(ld.y));
        dst[1] = make_float4(bfLO(ld.z), bfHI(ld.z), bfLO(ld.w), bfHI(ld.w));
    }
    __syncthreads();
    // ---- depthwise conv3 + complex pack: z[u] = x0c[2u] + i x0c[2u+1] ----
#pragma unroll
    for (int j = 0; j < 4; ++j) {
        int u = tid + (j << 8);
        float xm1 = (u == 0) ? 0.0f : rawF[2 * u - 1];
        float xc0 = rawF[2 * u];
        float xp1 = rawF[2 * u + 1];
        float xp2 = (u == 1023) ? 0.0f : rawF[2 * u + 2];
        float e = bv + w0 * xm1 + w1 * xc0 + w2 * xp1;
        float o = bv + w0 * xc0 + w1 * xp1 + w2 * xp2;
        A2[PADC(u)] = make_float2(e, o);
        A2[PADC(u + 1024)] = make_float2(0.0f, 0.0f);
    }
    fft2048c(A2, B2, tid);                          // fwd FFT of packed signal -> A2
    // ---- untangle, multiply by H, retangle (conj for inverse-via-forward) ----
    const float2* hf = Hf + (size_t)d * HSTRC;
#pragma unroll
    for (int j = 0; j < 4; ++j) {
        int k = 1 + tid + (j << 8);
        int m = 2048 - k;
        float2 zk = A2[PADC(k)], zm = A2[PADC(m)];
        float Er = 0.5f * (zk.x + zm.x), Ei = 0.5f * (zk.y - zm.y);
        float Or = 0.5f * (zk.y + zm.y), Oi = -0.5f * (zk.x - zm.x);
        float ts, tc;
        __sincosf(-1.5339807878856412e-3f * (float)k, &ts, &tc);
        float TOr = tc * Or - ts * Oi, TOi = tc * Oi + ts * Or;
        float Xpr = Er + TOr, Xpi = Ei + TOi;       // X[k]
        float Xmr = Er - TOr, Xmi = Ei - TOi;       // conj(X[m])
        float2 hk = hf[k], hm = hf[m];
        float Ykr = Xpr * hk.x - Xpi * hk.y, Yki = Xpr * hk.y + Xpi * hk.x;
        float Cr = Xmr * hm.x + Xmi * hm.y, Ci = Xmi * hm.x - Xmr * hm.y;
        float Pr = 0.5f * (Ykr + Cr), Pi = 0.5f * (Yki + Ci);
        float Gr = 0.5f * (Ykr - Cr), Gi = 0.5f * (Yki - Ci);
        float Qr = tc * Gr + ts * Gi, Qi = tc * Gi - ts * Gr;
        B2[PADC(k)] = make_float2(Pr - Qi, -(Pi + Qr));
        B2[PADC(m)] = make_float2(Pr + Qi, Pi - Qr);
    }
    if (tid == 0) {
        float2 z0 = A2[PADC(0)];
        float2 h0 = hf[0];
        float X0 = z0.x + z0.y, X2 = z0.x - z0.y;
        float Y0 = X0 * h0.x, Y2 = X2 * h0.y;
        float P = 0.5f * (Y0 + Y2), Q = 0.5f * (Y0 - Y2);
        B2[PADC(0)] = make_float2(P, -Q);
    }
    // ---- second forward FFT on conj(W) -> B2 holds conj(w~) ----
    stage8<0>(B2, A2, tid);
    stage8<3>(A2, B2, tid);
    stage8<6>(B2, A2, tid);
    stage4f(A2, B2, tid);
    __syncthreads();
    const float s = 1.0f / 2048.0f;
    unsigned* yrow = reinterpret_cast<unsigned*>(yT + (size_t)blk * LL);
#pragma unroll
    for (int j = 0; j < 4; ++j) {
        int u = tid + (j << 8);
        float2 v = B2[PADC(u)];
        float e = v.x * s, o = -v.y * s;
        yrow[u] = (unsigned)f2bf(e) | ((unsigned)f2bf(o) << 16);
    }
}

// ================= gate + transpose: yg(B,L,D) bf16 = yT * x1 * x2 =================
__global__ __launch_bounds__(256)
void gate_k(const unsigned short* __restrict__ yTb, const unsigned short* __restrict__ px,
            unsigned short* __restrict__ yg)
{
    __shared__ float t[64][65];
    const int tid = threadIdx.x;
    const int blk = blockIdx.x;
    const int b = blk >> 7;
    const int dt = (blk >> 5) & 3;
    const int lt = blk & 31;
    const int d0 = dt << 6, l0 = lt << 6;
    const int r0 = tid >> 6, c = tid & 63;
    for (int rr = 0; rr < 16; ++rr) {
        int dl = rr * 4 + r0;
        t[dl][c] = bf2f(yTb[(((size_t)(b << 8) + d0 + dl) << 11) + l0 + c]);
    }
    __syncthreads();
    const int lid = tid & 63, lr = tid >> 6;
    for (int k = 0; k < 16; ++k) {
        int ll = k * 4 + lr;
        int l = l0 + ll;
        size_t pb = ((size_t)(b * LL + l)) * 512;
        float v = t[lid][ll];
        float x1 = bf2f(px[pb + d0 + lid]);
        float x2 = bf2f(px[pb + 256 + d0 + lid]);
        yg[((size_t)(b * LL + l)) * DD + d0 + lid] = f2bf(v * x1 * x2);
    }
}

// ================= LN + cast to bf16 =================
__global__ __launch_bounds__(256)
void lncast_k(const float* __restrict__ xs, const float* __restrict__ g,
              const float* __restrict__ b, unsigned short* __restrict__ o)
{
    const int tid = threadIdx.x, lane = tid & 63, wave = tid >> 6;
    const size_t row = (size_t)blockIdx.x * 4 + wave;
    float4 v = reinterpret_cast<const float4*>(xs + row * DD)[lane];
    float s = v.x + v.y + v.z + v.w;
#pragma unroll
    for (int off = 32; off > 0; off >>= 1) s += __shfl_xor(s, off, 64);
    float mean = s * (1.0f / 256.0f);
    float e0 = v.x - mean, e1 = v.y - mean, e2 = v.z - mean, e3 = v.w - mean;
    float q = e0 * e0 + e1 * e1 + e2 * e2 + e3 * e3;
#pragma unroll
    for (int off = 32; off > 0; off >>= 1) q += __shfl_xor(q, off, 64);
    float rstd = rsqrtf(q * (1.0f / 256.0f) + 1e-5f);
    float4 gg = reinterpret_cast<const float4*>(g)[lane];
    float4 bb = reinterpret_cast<const float4*>(b)[lane];
    s16x4 r;
    r[0] = (short)f2bf(e0 * rstd * gg.x + bb.x);
    r[1] = (short)f2bf(e1 * rstd * gg.y + bb.y);
    r[2] = (short)f2bf(e2 * rstd * gg.z + bb.z);
    r[3] = (short)f2bf(e3 * rstd * gg.w + bb.w);
    *reinterpret_cast<s16x4*>(o + row * DD + lane * 4) = r;
}

// ================= weight cast + transpose =================
__global__ __launch_bounds__(256)
void wcastT_k(const float* __restrict__ W, unsigned short* __restrict__ WT, int K, int N)
{
    __shared__ float t[32][33];
    const int tx = threadIdx.x & 31, ty = threadIdx.x >> 5;
    const int n0 = blockIdx.x * 32, k0 = blockIdx.y * 32;
#pragma unroll
    for (int j = 0; j < 4; ++j)
        t[ty + 8 * j][tx] = W[(size_t)(k0 + ty + 8 * j) * N + n0 + tx];
    __syncthreads();
#pragma unroll
    for (int j = 0; j < 4; ++j)
        WT[(size_t)(n0 + ty + 8 * j) * K + k0 + tx] = f2bf(t[tx][ty + 8 * j]);
}

// ================= bf16 MFMA GEMM =================
// MODE 1: GELU -> bf16. MODE 2: += into f32. MODE 3: x0 transposed + x1x2 (in_proj).
template <int K, int N, int MODE>
__global__ __launch_bounds__(256)
void gemm_k(const unsigned short* __restrict__ A, const unsigned short* __restrict__ WT,
            const float* __restrict__ bias, void* __restrict__ outp, void* __restrict__ outp2)
{
    __shared__ unsigned short ldsA[8192];
    __shared__ unsigned short ldsB[8192];
    const int tid = threadIdx.x;
    const int lane = tid & 63, wid = tid >> 6;
    const int row0 = blockIdx.x * 128;
    const int col0 = blockIdx.y * 128;
    const int wm = (wid >> 1) * 64, wn = (wid & 1) * 64;
    const int fr = lane & 15, fg = lane >> 4;

    f32x4 acc[4][4];
#pragma unroll
    for (int n = 0; n < 4; ++n) {
        float bv = bias[col0 + wn + n * 16 + fr];
#pragma unroll
        for (int m = 0; m < 4; ++m) {
            acc[m][n][0] = bv; acc[m][n][1] = bv; acc[m][n][2] = bv; acc[m][n][3] = bv;
        }
    }

    const int srow = wid * 8 + (lane >> 3);
    const int sc = lane & 7;

    for (int kt = 0; kt < K / 64; ++kt) {
        const int k0 = kt * 64;
#pragma unroll
        for (int it = 0; it < 4; ++it) {
            int row = it * 32 + srow;
            int cs = sc ^ (row & 7);
            const char* ga = (const char*)(A + (size_t)(row0 + row) * K + k0) + cs * 16;
            const char* gb = (const char*)(WT + (size_t)(col0 + row) * K + k0) + cs * 16;
            GLL16(ga, (char*)ldsA + it * 4096 + wid * 1024);
            GLL16(gb, (char*)ldsB + it * 4096 + wid * 1024);
        }
        __syncthreads();
#pragma unroll
        for (int ks = 0; ks < 2; ++ks) {
            bf16x8 af[4], bf[4];
#pragma unroll
            for (int m = 0; m < 4; ++m) {
                int ar = wm + m * 16 + fr;
                int slot = (ks * 4 + fg) ^ (ar & 7);
                af[m] = *reinterpret_cast<const bf16x8*>(ldsA + ar * 64 + slot * 8);
            }
#pragma unroll
            for (int n = 0; n < 4; ++n) {
                int br = wn + n * 16 + fr;
                int slot = (ks * 4 + fg) ^ (br & 7);
                bf[n] = *reinterpret_cast<const bf16x8*>(ldsB + br * 64 + slot * 8);
            }
#pragma unroll
            for (int m = 0; m < 4; ++m)
#pragma unroll
                for (int n = 0; n < 4; ++n)
                    acc[m][n] = __builtin_amdgcn_mfma_f32_16x16x32_bf16(af[m], bf[n], acc[m][n], 0, 0, 0);
        }
        __syncthreads();
    }

    if constexpr (MODE == 3) {
        if (col0 < 256) {
            // x0: store transposed bf16 [b][d][l], 4 l-values packed per store
            const int b = row0 >> 11;
            const int lb0 = (row0 & (LL - 1)) + wm;
#pragma unroll
            for (int m = 0; m < 4; ++m) {
                int l = lb0 + m * 16 + fg * 4;
#pragma unroll
                for (int n = 0; n < 4; ++n) {
                    int dcol = col0 + wn + n * 16 + fr;
                    unsigned lo = (unsigned)f2bf(acc[m][n][0]) | ((unsigned)f2bf(acc[m][n][1]) << 16);
                    unsigned hi = (unsigned)f2bf(acc[m][n][2]) | ((unsigned)f2bf(acc[m][n][3]) << 16);
                    uint2 pk; pk.x = lo; pk.y = hi;
                    *reinterpret_cast<uint2*>((unsigned short*)outp +
                        (((size_t)(b << 8) + dcol) << 11) + l) = pk;
                }
            }
        } else {
            unsigned short* px = (unsigned short*)outp2;
#pragma unroll
            for (int m = 0; m < 4; ++m) {
                int gr = row0 + wm + m * 16 + fg * 4;
#pragma unroll
                for (int n = 0; n < 4; ++n) {
                    int gc = col0 - 256 + wn + n * 16 + fr;
#pragma unroll
                    for (int r = 0; r < 4; ++r)
                        px[(size_t)(gr + r) * 512 + gc] = f2bf(acc[m][n][r]);
                }
            }
        }
        return;
    }

#pragma unroll
    for (int m = 0; m < 4; ++m) {
        int gr = row0 + wm + m * 16 + fg * 4;
#pragma unroll
        for (int n = 0; n < 4; ++n) {
            int gc = col0 + wn + n * 16 + fr;
#pragma unroll
            for (int r = 0; r < 4; ++r) {
                float v = acc[m][n][r];
                if constexpr (MODE == 1) v = 0.5f * v * (1.0f + erff(v * 0.70710678118f));
                if constexpr (MODE <= 1) {
                    ((unsigned short*)outp)[(size_t)(gr + r) * N + gc] = f2bf(v);
                } else {
                    float* o = (float*)outp + (size_t)(gr + r) * N + gc;
                    *o += v;
                }
            }
        }
    }
}

// ================= mean pool (partial) =================
__global__ __launch_bounds__(256)
void pool_k(const float* __restrict__ xs, float* __restrict__ part)
{
    const int tid = threadIdx.x;
    const int b = blockIdx.x >> 4, g = blockIdx.x & 15;
    size_t base = ((size_t)b * LL + g * 128) * DD + tid;
    float s = 0.0f;
    for (int l = 0; l < 128; ++l) s += xs[base + (size_t)l * DD];
    part[(size_t)blockIdx.x * DD + tid] = s;
}

// ================= final =================
__global__ __launch_bounds__(256)
void final_k(const float* __restrict__ part, const float* __restrict__ ng,
             const float* __restrict__ nb, const float* __restrict__ cw,
             const float* __restrict__ cb, float* __restrict__ out)
{
    __shared__ float pl[256];
    __shared__ float red[4], red2[4];
    const int tid = threadIdx.x, b = blockIdx.x;
    float m = 0.0f;
    for (int g = 0; g < 16; ++g) m += part[((size_t)b * 16 + g) * DD + tid];
    m *= (1.0f / (float)LL);
    const int lane = tid & 63, wave = tid >> 6;
    float s = m;
#pragma unroll
    for (int off = 32; off > 0; off >>= 1) s += __shfl_xor(s, off, 64);
    if (lane == 0) red[wave] = s;
    __syncthreads();
    float mean = (red[0] + red[1] + red[2] + red[3]) * (1.0f / 256.0f);
    float dm = m - mean;
    float qv = dm * dm;
#pragma unroll
    for (int off = 32; off > 0; off >>= 1) qv += __shfl_xor(qv, off, 64);
    if (lane == 0) red2[wave] = qv;
    __syncthreads();
    float var = (red2[0] + red2[1] + red2[2] + red2[3]) * (1.0f / 256.0f);
    pl[tid] = dm * rsqrtf(var + 1e-5f) * ng[tid] + nb[tid];
    __syncthreads();
    if (tid < NCLS) {
        float a = cb[tid];
        for (int dd = 0; dd < 256; ++dd) a += pl[dd] * cw[dd * NCLS + tid];
        out[b * NCLS + tid] = a;
    }
}

// ================= launcher =================
extern "C" void kernel_launch(void* const* d_in, const int* in_sizes, int n_in,
                              void* d_out, int out_size, void* d_ws, size_t ws_size,
                              hipStream_t stream)
{
    (void)in_sizes; (void)n_in; (void)out_size; (void)ws_size;
    const float* x        = (const float*)d_in[0];
    const float* inp_w    = (const float*)d_in[1];
    const float* inp_b    = (const float*)d_in[2];
    const float* in_proj_w= (const float*)d_in[3];
    const float* in_proj_b= (const float*)d_in[4];
    const float* short_w  = (const float*)d_in[5];
    const float* short_b  = (const float*)d_in[6];
    const float* filt_w1  = (const float*)d_in[7];
    const float* filt_b1  = (const float*)d_in[8];
    const float* filt_w2  = (const float*)d_in[9];
    const float* filt_b2  = (const float*)d_in[10];
    const float* out_w    = (const float*)d_in[11];
    const float* out_b    = (const float*)d_in[12];
    const float* ln1_g    = (const float*)d_in[13];
    const float* ln1_b    = (const float*)d_in[14];
    const float* ln2_g    = (const float*)d_in[15];
    const float* ln2_b    = (const float*)d_in[16];
    const float* ffn_w1   = (const float*)d_in[17];
    const float* ffn_b1   = (const float*)d_in[18];
    const float* ffn_w2   = (const float*)d_in[19];
    const float* ffn_b2   = (const float*)d_in[20];
    const float* norm_g   = (const float*)d_in[21];
    const float* norm_b   = (const float*)d_in[22];
    const float* cls_w    = (const float*)d_in[23];
    const float* cls_b    = (const float*)d_in[24];

    float* ws = (float*)d_ws;
    float* xs            = ws;                                  // 32MB f32
    unsigned short* xln  = (unsigned short*)(ws + 8388608);     // 16MB bf16
    unsigned short* x0T  = (unsigned short*)(ws + 12582912);    // 16MB bf16 [B][D][L]
    unsigned short* yT   = (unsigned short*)(ws + 16777216);    // 16MB bf16 [B][D][L]
    unsigned short* projx= (unsigned short*)(ws + 20971520);    // 32MB bf16 (x1,x2)
    unsigned short* ygp  = x0T;                                 // reuse x0T after fftconv
    unsigned short* hid  = x0T;                                 // 64MB bf16 span (x0T..projx)
    float* hT            = ws + 29360128;                       // 2MB
    float2* Hf           = (float2*)(ws + 29884416);            // 256*2056 float2
    float* part          = ws + 30937088;
    unsigned short* WTb  = (unsigned short*)(ws + 31002624);    // 4 x 786432 bf16

    for (int i = 0; i < NLAYERS; ++i) {
        unsigned short* wt = WTb + (size_t)i * 786432;
        wcastT_k<<<dim3(24, 8), 256, 0, stream>>>(in_proj_w + (size_t)i * 196608, wt, 256, 768);
        wcastT_k<<<dim3(8, 8), 256, 0, stream>>>(out_w + (size_t)i * 65536, wt + 196608, 256, 256);
        wcastT_k<<<dim3(32, 8), 256, 0, stream>>>(ffn_w1 + (size_t)i * 262144, wt + 262144, 256, 1024);
        wcastT_k<<<dim3(8, 32), 256, 0, stream>>>(ffn_w2 + (size_t)i * 262144, wt + 524288, 1024, 256);
    }

    embed_k<<<4096, 256, 0, stream>>>(x, inp_w, inp_b, xs);

    for (int i = 0; i < NLAYERS; ++i) {
        unsigned short* wt = WTb + (size_t)i * 786432;
        filt_k<<<LL, 256, 0, stream>>>(filt_w1 + i * 1024, filt_b1 + i * 64,
                                       filt_w2 + i * 16384, filt_b2 + i * 256, hT);
        ffth_k<<<DD, 256, 0, stream>>>(hT, Hf);
        lncast_k<<<8192, 256, 0, stream>>>(xs, ln1_g + i * 256, ln1_b + i * 256, xln);
        gemm_k<256, 768, 3><<<dim3(256, 6), 256, 0, stream>>>(
            xln, wt, in_proj_b + i * 768, x0T, projx);
        fftconv_k<<<4096, 256, 0, stream>>>(x0T, yT, Hf, short_w + i * 768, short_b + i * 256);
        gate_k<<<2048, 256, 0, stream>>>(yT, projx, ygp);
        gemm_k<256, 256, 2><<<dim3(256, 2), 256, 0, stream>>>(
            ygp, wt + 196608, out_b + i * 256, xs, nullptr);
        lncast_k<<<8192, 256, 0, stream>>>(xs, ln2_g + i * 256, ln2_b + i * 256, xln);
        gemm_k<256, 1024, 1><<<dim3(256, 8), 256, 0, stream>>>(
            xln, wt + 262144, ffn_b1 + i * 1024, hid, nullptr);
        gemm_k<1024, 256, 2><<<dim3(256, 2), 256, 0, stream>>>(
            hid, wt + 524288, ffn_b2 + i * 256, xs, nullptr);
    }

    pool_k<<<BB * 16, 256, 0, stream>>>(xs, part);
    final_k<<<BB, 256, 0, stream>>>(part, norm_g, norm_b, cls_w, cls_b, (float*)d_out);
}

// Round 5
// 788.953 us; speedup vs baseline: 5.8454x; 1.1204x over previous
//
#include <hip/hip_runtime.h>
#include <math.h>

// ---------------- model constants ----------------
#define BB 16
#define LL 2048
#define CHUNK 10
#define DD 256
#define NLAYERS 4
#define FFD 1024
#define NCLS 10
#define HSTRC 2056  // float2 stride per channel of Hf (2049 bins + pad)

typedef short bf16x8 __attribute__((ext_vector_type(8)));
typedef short s16x4 __attribute__((ext_vector_type(4)));
typedef float f32x4 __attribute__((ext_vector_type(4)));

__device__ __forceinline__ unsigned short f2bf(float f) {
    unsigned int u = __builtin_bit_cast(unsigned int, f);
    u = (u + 0x7FFF + ((u >> 16) & 1)) >> 16;
    return (unsigned short)u;
}
__device__ __forceinline__ float bf2f(unsigned short s) {
    unsigned int u = ((unsigned int)s) << 16;
    return __builtin_bit_cast(float, u);
}
__device__ __forceinline__ float bfLO(unsigned v) { return __builtin_bit_cast(float, v << 16); }
__device__ __forceinline__ float bfHI(unsigned v) { return __builtin_bit_cast(float, v & 0xFFFF0000u); }

#define PADC(a) ((a) + ((a) >> 4))

__device__ __forceinline__ float2 cmulf(float2 a, float2 b) {
    return make_float2(fmaf(-a.y, b.y, a.x * b.x), fmaf(a.y, b.x, a.x * b.y));
}

#define GLL16(gsrc, ldst) \
    __builtin_amdgcn_global_load_lds((const __attribute__((address_space(1))) void*)(gsrc), \
                                     (__attribute__((address_space(3))) void*)(ldst), 16, 0, 0)

// ================= embed =================
__global__ __launch_bounds__(256)
void embed_k(const float* __restrict__ x, const float* __restrict__ iw,
             const float* __restrict__ ib, float* __restrict__ xs)
{
    const int tid = threadIdx.x;
    const size_t row0 = (size_t)blockIdx.x * 8;
    const int i2 = (tid >> 1) * 2;
    const float div = expf(-0.03597789207803197f * (float)i2);
    float wcol[CHUNK];
#pragma unroll
    for (int c = 0; c < CHUNK; ++c) wcol[c] = iw[c * DD + tid];
    const float bv = ib[tid];
    for (int rr = 0; rr < 8; ++rr) {
        size_t row = row0 + rr;
        int l = (int)(row & (LL - 1));
        const float* xr = x + row * CHUNK;
        float acc = bv;
#pragma unroll
        for (int c = 0; c < CHUNK; ++c) acc += xr[c] * wcol[c];
        float sv, cv;
        sincosf((float)l * div, &sv, &cv);
        acc += (tid & 1) ? cv : sv;
        xs[row * DD + tid] = acc;
    }
}

// ================= filter MLP -> hT[d][l] =================
__global__ __launch_bounds__(256)
void filt_k(const float* __restrict__ fw1, const float* __restrict__ fb1,
            const float* __restrict__ fw2, const float* __restrict__ fb2,
            float* __restrict__ hT)
{
    __shared__ float pe[16];
    __shared__ float hid[64];
    const int tid = threadIdx.x, l = blockIdx.x;
    if (tid < 16) {
        int i2 = (tid >> 1) * 2;
        float div = expf(-0.5756462732485114f * (float)i2);
        float sv, cv;
        sincosf((float)l * div, &sv, &cv);
        pe[tid] = (tid & 1) ? cv : sv;
    }
    __syncthreads();
    if (tid < 64) {
        float a = fb1[tid];
#pragma unroll
        for (int e = 0; e < 16; ++e) a += pe[e] * fw1[e * 64 + tid];
        hid[tid] = 0.5f * a * (1.0f + erff(a * 0.70710678118f));
    }
    __syncthreads();
    float a = fb2[tid];
#pragma unroll
    for (int h = 0; h < 64; ++h) a += hid[h] * fw2[h * DD + tid];
    hT[(size_t)tid * LL + l] = a;
}

// ================= radix-8 Stockham FFT core, N=2048 = 8*8*8*4, float2 LDS =================
__device__ __forceinline__ void dft4c(float2 a, float2 b, float2 c, float2 d,
                                      float2& F0, float2& F1, float2& F2, float2& F3)
{
    float t0r = a.x + c.x, t0i = a.y + c.y;
    float t1r = a.x - c.x, t1i = a.y - c.y;
    float t2r = b.x + d.x, t2i = b.y + d.y;
    float t3r = b.x - d.x, t3i = b.y - d.y;
    F0 = make_float2(t0r + t2r, t0i + t2i);
    F2 = make_float2(t0r - t2r, t0i - t2i);
    F1 = make_float2(t1r + t3i, t1i - t3r);   // t1 - i*t3
    F3 = make_float2(t1r - t3i, t1i + t3r);   // t1 + i*t3
}

template <int SH>
__device__ __forceinline__ void stage8(const float2* __restrict__ src,
                                       float2* __restrict__ dst, int tid)
{
    constexpr int ST = 1 << SH;
    __syncthreads();
    const int p = tid >> SH;
    const int q = tid & (ST - 1);
    float2 x0 = src[PADC(tid)];
    float2 x1 = src[PADC(tid + 256)];
    float2 x2 = src[PADC(tid + 512)];
    float2 x3 = src[PADC(tid + 768)];
    float2 x4 = src[PADC(tid + 1024)];
    float2 x5 = src[PADC(tid + 1280)];
    float2 x6 = src[PADC(tid + 1536)];
    float2 x7 = src[PADC(tid + 1792)];
    float2 E0, E1, E2, E3, O0, O1, O2, O3;
    dft4c(x0, x2, x4, x6, E0, E1, E2, E3);
    dft4c(x1, x3, x5, x7, O0, O1, O2, O3);
    const float C8 = 0.70710678118654752f;
    float2 y0 = make_float2(E0.x + O0.x, E0.y + O0.y);
    float2 y4 = make_float2(E0.x - O0.x, E0.y - O0.y);
    float a1 = C8 * (O1.x + O1.y), b1 = C8 * (O1.y - O1.x);       // w8^1 * O1
    float2 y1 = make_float2(E1.x + a1, E1.y + b1);
    float2 y5 = make_float2(E1.x - a1, E1.y - b1);
    float2 y2 = make_float2(E2.x + O2.y, E2.y - O2.x);            // -i * O2
    float2 y6 = make_float2(E2.x - O2.y, E2.y + O2.x);
    float a3 = -C8 * (O3.x - O3.y), b3 = -C8 * (O3.x + O3.y);     // w8^3 * O3
    float2 y3 = make_float2(E3.x + a3, E3.y + b3);
    float2 y7 = make_float2(E3.x - a3, E3.y - b3);
    const int k0 = p << SH;
    float s1, c1;
    __sincosf(-3.0679615757712823e-3f * (float)k0, &s1, &c1);     // -2pi/2048 * k0
    float2 w1 = make_float2(c1, s1);
    float2 w2 = cmulf(w1, w1);
    float2 w3 = cmulf(w2, w1);
    float2 w4 = cmulf(w2, w2);
    float2 w5 = cmulf(w3, w2);
    float2 w6 = cmulf(w3, w3);
    float2 w7 = cmulf(w4, w3);
    const int ob = q + ((ST * p) << 3);
    dst[PADC(ob)] = y0;
    dst[PADC(ob + ST)] = cmulf(w1, y1);
    dst[PADC(ob + 2 * ST)] = cmulf(w2, y2);
    dst[PADC(ob + 3 * ST)] = cmulf(w3, y3);
    dst[PADC(ob + 4 * ST)] = cmulf(w4, y4);
    dst[PADC(ob + 5 * ST)] = cmulf(w5, y5);
    dst[PADC(ob + 6 * ST)] = cmulf(w6, y6);
    dst[PADC(ob + 7 * ST)] = cmulf(w7, y7);
}

// final radix-4 stage, st=512, twiddle-free (p=0)
__device__ __forceinline__ void stage4f(const float2* __restrict__ src,
                                        float2* __restrict__ dst, int tid)
{
    __syncthreads();
#pragma unroll
    for (int jj = 0; jj < 2; ++jj) {
        int u = tid + (jj << 8);
        float2 a = src[PADC(u)], b = src[PADC(u + 512)];
        float2 c = src[PADC(u + 1024)], d = src[PADC(u + 1536)];
        float2 F0, F1, F2, F3;
        dft4c(a, b, c, d, F0, F1, F2, F3);
        dst[PADC(u)] = F0;
        dst[PADC(u + 512)] = F1;
        dst[PADC(u + 1024)] = F2;
        dst[PADC(u + 1536)] = F3;
    }
}

// full FFT: data in A -> result in A (A->B->A->B->A), trailing barrier included
__device__ __forceinline__ void fft2048c(float2* __restrict__ A, float2* __restrict__ B, int tid)
{
    stage8<0>(A, B, tid);
    stage8<3>(B, A, tid);
    stage8<6>(A, B, tid);
    stage4f(B, A, tid);
    __syncthreads();
}

// ================= Hf = rfft_4096(zero-pad(h)) per channel, interleaved =================
__global__ __launch_bounds__(256)
void ffth_k(const float* __restrict__ hT, float2* __restrict__ Hf)
{
    __shared__ float2 A2[2176], B2[2176];
    const int tid = threadIdx.x, d = blockIdx.x;
    const float2* rowf = reinterpret_cast<const float2*>(hT + (size_t)d * LL);
#pragma unroll
    for (int j = 0; j < 4; ++j) {
        int u = tid + (j << 8);
        A2[PADC(u)] = rowf[u];                      // z[u] = h[2u] + i h[2u+1]
        A2[PADC(u + 1024)] = make_float2(0.0f, 0.0f);
    }
    fft2048c(A2, B2, tid);
    float2* hf = Hf + (size_t)d * HSTRC;
#pragma unroll
    for (int j = 0; j < 4; ++j) {
        int k = 1 + tid + (j << 8);                 // k in [1,1024]
        int m = 2048 - k;
        float2 zk = A2[PADC(k)], zm = A2[PADC(m)];
        float Er = 0.5f * (zk.x + zm.x), Ei = 0.5f * (zk.y - zm.y);
        float Or = 0.5f * (zk.y + zm.y), Oi = -0.5f * (zk.x - zm.x);
        float ts, tc;
        __sincosf(-1.5339807878856412e-3f * (float)k, &ts, &tc);  // -2pi/4096 * k
        float TOr = tc * Or - ts * Oi, TOi = tc * Oi + ts * Or;
        hf[k] = make_float2(Er + TOr, Ei + TOi);                  // H[k]
        hf[m] = make_float2(Er - TOr, -(Ei - TOi));               // H[2048-k]
    }
    if (tid == 0) {
        float2 z0 = A2[PADC(0)];
        hf[0] = make_float2(z0.x + z0.y, z0.x - z0.y);            // (H[0], H[2048])
    }
}

// ================= fused conv3 + fft conv: x0T(bf16, field-swap layout) -> yT(bf16) =================
__global__ __launch_bounds__(256)
void fftconv_k(const unsigned short* __restrict__ x0T, unsigned short* __restrict__ yT,
               const float2* __restrict__ Hf, const float* __restrict__ sw,
               const float* __restrict__ sb)
{
    __shared__ float2 A2[2176], B2[2176];
    const int tid = threadIdx.x;
    // XCD-locality swizzle: XCD c handles channels d in [32c, 32c+32), all b
    const int w = blockIdx.x;
    const int c = w & 7, s = w >> 3;
    const int d = c * 32 + (s & 31);
    const int b = s >> 5;
    const int blk = b * 256 + d;
    const float w0 = sw[d * 3], w1 = sw[d * 3 + 1], w2 = sw[d * 3 + 2];
    const float bv = sb[d];

    // ---- load bf16 row (field-swap permuted within 64-blocks) into LDS floats ----
    float* rawF = reinterpret_cast<float*>(B2);
    {
        const uint4* rowv = reinterpret_cast<const uint4*>(x0T + (size_t)blk * LL);
        uint4 ld = rowv[tid];
        int p = tid << 3;                 // stored position of first bf16
        int lB = p & ~63;
        int p6 = p & 63;
        int fg = p6 >> 4;
        int m0 = (p6 >> 2) & 3;           // in {0, 2}
        float4* d0 = reinterpret_cast<float4*>(rawF + lB + m0 * 16 + fg * 4);
        float4* d1 = reinterpret_cast<float4*>(rawF + lB + (m0 + 1) * 16 + fg * 4);
        *d0 = make_float4(bfLO(ld.x), bfHI(ld.x), bfLO(ld.y), bfHI(ld.y));
        *d1 = make_float4(bfLO(ld.z), bfHI(ld.z), bfLO(ld.w), bfHI(ld.w));
    }
    __syncthreads();
    // ---- depthwise conv3 + complex pack: z[u] = x0c[2u] + i x0c[2u+1] ----
#pragma unroll
    for (int j = 0; j < 4; ++j) {
        int u = tid + (j << 8);
        float xm1 = (u == 0) ? 0.0f : rawF[2 * u - 1];
        float xc0 = rawF[2 * u];
        float xp1 = rawF[2 * u + 1];
        float xp2 = (u == 1023) ? 0.0f : rawF[2 * u + 2];
        float e = bv + w0 * xm1 + w1 * xc0 + w2 * xp1;
        float o = bv + w0 * xc0 + w1 * xp1 + w2 * xp2;
        A2[PADC(u)] = make_float2(e, o);
        A2[PADC(u + 1024)] = make_float2(0.0f, 0.0f);
    }
    fft2048c(A2, B2, tid);                          // fwd FFT of packed signal -> A2
    // ---- untangle, multiply by H, retangle (conj for inverse-via-forward) ----
    const float2* hf = Hf + (size_t)d * HSTRC;
#pragma unroll
    for (int j = 0; j < 4; ++j) {
        int k = 1 + tid + (j << 8);
        int m = 2048 - k;
        float2 zk = A2[PADC(k)], zm = A2[PADC(m)];
        float Er = 0.5f * (zk.x + zm.x), Ei = 0.5f * (zk.y - zm.y);
        float Or = 0.5f * (zk.y + zm.y), Oi = -0.5f * (zk.x - zm.x);
        float ts, tc;
        __sincosf(-1.5339807878856412e-3f * (float)k, &ts, &tc);
        float TOr = tc * Or - ts * Oi, TOi = tc * Oi + ts * Or;
        float Xpr = Er + TOr, Xpi = Ei + TOi;       // X[k]
        float Xmr = Er - TOr, Xmi = Ei - TOi;       // conj(X[m])
        float2 hk = hf[k], hm = hf[m];
        float Ykr = Xpr * hk.x - Xpi * hk.y, Yki = Xpr * hk.y + Xpi * hk.x;
        float Cr = Xmr * hm.x + Xmi * hm.y, Ci = Xmi * hm.x - Xmr * hm.y;
        float Pr = 0.5f * (Ykr + Cr), Pi = 0.5f * (Yki + Ci);
        float Gr = 0.5f * (Ykr - Cr), Gi = 0.5f * (Yki - Ci);
        float Qr = tc * Gr + ts * Gi, Qi = tc * Gi - ts * Gr;
        B2[PADC(k)] = make_float2(Pr - Qi, -(Pi + Qr));
        B2[PADC(m)] = make_float2(Pr + Qi, Pi - Qr);
    }
    if (tid == 0) {
        float2 z0 = A2[PADC(0)];
        float2 h0 = hf[0];
        float X0 = z0.x + z0.y, X2 = z0.x - z0.y;
        float Y0 = X0 * h0.x, Y2 = X2 * h0.y;
        float P = 0.5f * (Y0 + Y2), Q = 0.5f * (Y0 - Y2);
        B2[PADC(0)] = make_float2(P, -Q);
    }
    // ---- second forward FFT on conj(W) -> B2 holds conj(w~) ----
    stage8<0>(B2, A2, tid);
    stage8<3>(A2, B2, tid);
    stage8<6>(B2, A2, tid);
    stage4f(A2, B2, tid);
    __syncthreads();
    const float sc = 1.0f / 2048.0f;
    unsigned* yrow = reinterpret_cast<unsigned*>(yT + (size_t)blk * LL);
#pragma unroll
    for (int j = 0; j < 4; ++j) {
        int u = tid + (j << 8);
        float2 v = B2[PADC(u)];
        float e = v.x * sc, o = -v.y * sc;
        yrow[u] = (unsigned)f2bf(e) | ((unsigned)f2bf(o) << 16);
    }
}

// ================= gate + transpose: yg(B,L,D) bf16 = yT * x1 * x2 =================
__global__ __launch_bounds__(256)
void gate_k(const unsigned short* __restrict__ yTb, const unsigned short* __restrict__ px,
            unsigned short* __restrict__ yg)
{
    __shared__ float t[64][65];
    const int tid = threadIdx.x;
    const int blk = blockIdx.x;
    const int b = blk >> 7;
    const int dt = (blk >> 5) & 3;
    const int lt = blk & 31;
    const int d0 = dt << 6, l0 = lt << 6;
    const int r0 = tid >> 6, c = tid & 63;
    for (int rr = 0; rr < 16; ++rr) {
        int dl = rr * 4 + r0;
        t[dl][c] = bf2f(yTb[(((size_t)(b << 8) + d0 + dl) << 11) + l0 + c]);
    }
    __syncthreads();
    const int lid = tid & 63, lr = tid >> 6;
    for (int k = 0; k < 16; ++k) {
        int ll = k * 4 + lr;
        int l = l0 + ll;
        size_t pb = ((size_t)(b * LL + l)) * 512;
        float v = t[lid][ll];
        float x1 = bf2f(px[pb + d0 + lid]);
        float x2 = bf2f(px[pb + 256 + d0 + lid]);
        yg[((size_t)(b * LL + l)) * DD + d0 + lid] = f2bf(v * x1 * x2);
    }
}

// ================= LN + cast to bf16 =================
__global__ __launch_bounds__(256)
void lncast_k(const float* __restrict__ xs, const float* __restrict__ g,
              const float* __restrict__ b, unsigned short* __restrict__ o)
{
    const int tid = threadIdx.x, lane = tid & 63, wave = tid >> 6;
    const size_t row = (size_t)blockIdx.x * 4 + wave;
    float4 v = reinterpret_cast<const float4*>(xs + row * DD)[lane];
    float s = v.x + v.y + v.z + v.w;
#pragma unroll
    for (int off = 32; off > 0; off >>= 1) s += __shfl_xor(s, off, 64);
    float mean = s * (1.0f / 256.0f);
    float e0 = v.x - mean, e1 = v.y - mean, e2 = v.z - mean, e3 = v.w - mean;
    float q = e0 * e0 + e1 * e1 + e2 * e2 + e3 * e3;
#pragma unroll
    for (int off = 32; off > 0; off >>= 1) q += __shfl_xor(q, off, 64);
    float rstd = rsqrtf(q * (1.0f / 256.0f) + 1e-5f);
    float4 gg = reinterpret_cast<const float4*>(g)[lane];
    float4 bb = reinterpret_cast<const float4*>(b)[lane];
    s16x4 r;
    r[0] = (short)f2bf(e0 * rstd * gg.x + bb.x);
    r[1] = (short)f2bf(e1 * rstd * gg.y + bb.y);
    r[2] = (short)f2bf(e2 * rstd * gg.z + bb.z);
    r[3] = (short)f2bf(e3 * rstd * gg.w + bb.w);
    *reinterpret_cast<s16x4*>(o + row * DD + lane * 4) = r;
}

// ================= weight cast + transpose =================
__global__ __launch_bounds__(256)
void wcastT_k(const float* __restrict__ W, unsigned short* __restrict__ WT, int K, int N)
{
    __shared__ float t[32][33];
    const int tx = threadIdx.x & 31, ty = threadIdx.x >> 5;
    const int n0 = blockIdx.x * 32, k0 = blockIdx.y * 32;
#pragma unroll
    for (int j = 0; j < 4; ++j)
        t[ty + 8 * j][tx] = W[(size_t)(k0 + ty + 8 * j) * N + n0 + tx];
    __syncthreads();
#pragma unroll
    for (int j = 0; j < 4; ++j)
        WT[(size_t)(n0 + ty + 8 * j) * K + k0 + tx] = f2bf(t[tx][ty + 8 * j]);
}

// ================= bf16 MFMA GEMM =================
// 1D grid with XCD-chunk swizzle; cols iterate fastest within a row-panel -> A reuse in L2.
// MODE 1: GELU -> bf16. MODE 2: += into f32. MODE 3: x0 transposed(field-swap) + x1x2.
template <int K, int N, int MODE>
__global__ __launch_bounds__(256)
void gemm_k(const unsigned short* __restrict__ A, const unsigned short* __restrict__ WT,
            const float* __restrict__ bias, void* __restrict__ outp, void* __restrict__ outp2)
{
    constexpr int C = N / 128;
    __shared__ unsigned short ldsA[8192];
    __shared__ unsigned short ldsB[8192];
    const int tid = threadIdx.x;
    const int lane = tid & 63, wid = tid >> 6;
    const int nwg = gridDim.x;
    const int w = blockIdx.x;
    const int logical = (w & 7) * (nwg >> 3) + (w >> 3);
    const int row0 = (logical / C) * 128;
    const int col0 = (logical % C) * 128;
    const int wm = (wid >> 1) * 64, wn = (wid & 1) * 64;
    const int fr = lane & 15, fg = lane >> 4;

    f32x4 acc[4][4];
#pragma unroll
    for (int n = 0; n < 4; ++n) {
        float bv = bias[col0 + wn + n * 16 + fr];
#pragma unroll
        for (int m = 0; m < 4; ++m) {
            acc[m][n][0] = bv; acc[m][n][1] = bv; acc[m][n][2] = bv; acc[m][n][3] = bv;
        }
    }

    const int srow = wid * 8 + (lane >> 3);
    const int sc = lane & 7;

    for (int kt = 0; kt < K / 64; ++kt) {
        const int k0 = kt * 64;
#pragma unroll
        for (int it = 0; it < 4; ++it) {
            int row = it * 32 + srow;
            int cs = sc ^ (row & 7);
            const char* ga = (const char*)(A + (size_t)(row0 + row) * K + k0) + cs * 16;
            const char* gb = (const char*)(WT + (size_t)(col0 + row) * K + k0) + cs * 16;
            GLL16(ga, (char*)ldsA + it * 4096 + wid * 1024);
            GLL16(gb, (char*)ldsB + it * 4096 + wid * 1024);
        }
        __syncthreads();
#pragma unroll
        for (int ks = 0; ks < 2; ++ks) {
            bf16x8 af[4], bf[4];
#pragma unroll
            for (int m = 0; m < 4; ++m) {
                int ar = wm + m * 16 + fr;
                int slot = (ks * 4 + fg) ^ (ar & 7);
                af[m] = *reinterpret_cast<const bf16x8*>(ldsA + ar * 64 + slot * 8);
            }
#pragma unroll
            for (int n = 0; n < 4; ++n) {
                int br = wn + n * 16 + fr;
                int slot = (ks * 4 + fg) ^ (br & 7);
                bf[n] = *reinterpret_cast<const bf16x8*>(ldsB + br * 64 + slot * 8);
            }
#pragma unroll
            for (int m = 0; m < 4; ++m)
#pragma unroll
                for (int n = 0; n < 4; ++n)
                    acc[m][n] = __builtin_amdgcn_mfma_f32_16x16x32_bf16(af[m], bf[n], acc[m][n], 0, 0, 0);
        }
        __syncthreads();
    }

    if constexpr (MODE == 3) {
        if (col0 < 256) {
            // x0: transposed bf16 [b][d][l'], field-swap within each 64-l block:
            // stored pos p = fg*16 + m*4 + r  holds value at l = m*16 + fg*4 + r.
            // => each lane stores 2 x 16B contiguous (full cache-line friendly).
            const int b = row0 >> 11;
            const int lb0 = (row0 & (LL - 1)) + wm;
#pragma unroll
            for (int n = 0; n < 4; ++n) {
                int dcol = col0 + wn + n * 16 + fr;
                unsigned short* dst = (unsigned short*)outp +
                    (((size_t)(b << 8) + dcol) << 11) + lb0 + fg * 16;
                unsigned pk[8];
#pragma unroll
                for (int q = 0; q < 8; ++q) {
                    int m = q >> 1, r0 = (q & 1) * 2;
                    pk[q] = (unsigned)f2bf(acc[m][n][r0]) | ((unsigned)f2bf(acc[m][n][r0 + 1]) << 16);
                }
                *reinterpret_cast<uint4*>(dst)     = make_uint4(pk[0], pk[1], pk[2], pk[3]);
                *reinterpret_cast<uint4*>(dst + 8) = make_uint4(pk[4], pk[5], pk[6], pk[7]);
            }
        } else {
            unsigned short* px = (unsigned short*)outp2;
#pragma unroll
            for (int m = 0; m < 4; ++m) {
                int gr = row0 + wm + m * 16 + fg * 4;
#pragma unroll
                for (int n = 0; n < 4; ++n) {
                    int gc = col0 - 256 + wn + n * 16 + fr;
#pragma unroll
                    for (int r = 0; r < 4; ++r)
                        px[(size_t)(gr + r) * 512 + gc] = f2bf(acc[m][n][r]);
                }
            }
        }
        return;
    }

#pragma unroll
    for (int m = 0; m < 4; ++m) {
        int gr = row0 + wm + m * 16 + fg * 4;
#pragma unroll
        for (int n = 0; n < 4; ++n) {
            int gc = col0 + wn + n * 16 + fr;
#pragma unroll
            for (int r = 0; r < 4; ++r) {
                float v = acc[m][n][r];
                if constexpr (MODE == 1) v = 0.5f * v * (1.0f + erff(v * 0.70710678118f));
                if constexpr (MODE <= 1) {
                    ((unsigned short*)outp)[(size_t)(gr + r) * N + gc] = f2bf(v);
                } else {
                    float* o = (float*)outp + (size_t)(gr + r) * N + gc;
                    *o += v;
                }
            }
        }
    }
}

// ================= mean pool (partial) =================
__global__ __launch_bounds__(256)
void pool_k(const float* __restrict__ xs, float* __restrict__ part)
{
    const int tid = threadIdx.x;
    const int b = blockIdx.x >> 4, g = blockIdx.x & 15;
    size_t base = ((size_t)b * LL + g * 128) * DD + tid;
    float s = 0.0f;
    for (int l = 0; l < 128; ++l) s += xs[base + (size_t)l * DD];
    part[(size_t)blockIdx.x * DD + tid] = s;
}

// ================= final =================
__global__ __launch_bounds__(256)
void final_k(const float* __restrict__ part, const float* __restrict__ ng,
             const float* __restrict__ nb, const float* __restrict__ cw,
             const float* __restrict__ cb, float* __restrict__ out)
{
    __shared__ float pl[256];
    __shared__ float red[4], red2[4];
    const int tid = threadIdx.x, b = blockIdx.x;
    float m = 0.0f;
    for (int g = 0; g < 16; ++g) m += part[((size_t)b * 16 + g) * DD + tid];
    m *= (1.0f / (float)LL);
    const int lane = tid & 63, wave = tid >> 6;
    float s = m;
#pragma unroll
    for (int off = 32; off > 0; off >>= 1) s += __shfl_xor(s, off, 64);
    if (lane == 0) red[wave] = s;
    __syncthreads();
    float mean = (red[0] + red[1] + red[2] + red[3]) * (1.0f / 256.0f);
    float dm = m - mean;
    float qv = dm * dm;
#pragma unroll
    for (int off = 32; off > 0; off >>= 1) qv += __shfl_xor(qv, off, 64);
    if (lane == 0) red2[wave] = qv;
    __syncthreads();
    float var = (red2[0] + red2[1] + red2[2] + red2[3]) * (1.0f / 256.0f);
    pl[tid] = dm * rsqrtf(var + 1e-5f) * ng[tid] + nb[tid];
    __syncthreads();
    if (tid < NCLS) {
        float a = cb[tid];
        for (int dd = 0; dd < 256; ++dd) a += pl[dd] * cw[dd * NCLS + tid];
        out[b * NCLS + tid] = a;
    }
}

// ================= launcher =================
extern "C" void kernel_launch(void* const* d_in, const int* in_sizes, int n_in,
                              void* d_out, int out_size, void* d_ws, size_t ws_size,
                              hipStream_t stream)
{
    (void)in_sizes; (void)n_in; (void)out_size; (void)ws_size;
    const float* x        = (const float*)d_in[0];
    const float* inp_w    = (const float*)d_in[1];
    const float* inp_b    = (const float*)d_in[2];
    const float* in_proj_w= (const float*)d_in[3];
    const float* in_proj_b= (const float*)d_in[4];
    const float* short_w  = (const float*)d_in[5];
    const float* short_b  = (const float*)d_in[6];
    const float* filt_w1  = (const float*)d_in[7];
    const float* filt_b1  = (const float*)d_in[8];
    const float* filt_w2  = (const float*)d_in[9];
    const float* filt_b2  = (const float*)d_in[10];
    const float* out_w    = (const float*)d_in[11];
    const float* out_b    = (const float*)d_in[12];
    const float* ln1_g    = (const float*)d_in[13];
    const float* ln1_b    = (const float*)d_in[14];
    const float* ln2_g    = (const float*)d_in[15];
    const float* ln2_b    = (const float*)d_in[16];
    const float* ffn_w1   = (const float*)d_in[17];
    const float* ffn_b1   = (const float*)d_in[18];
    const float* ffn_w2   = (const float*)d_in[19];
    const float* ffn_b2   = (const float*)d_in[20];
    const float* norm_g   = (const float*)d_in[21];
    const float* norm_b   = (const float*)d_in[22];
    const float* cls_w    = (const float*)d_in[23];
    const float* cls_b    = (const float*)d_in[24];

    float* ws = (float*)d_ws;
    float* xs            = ws;                                  // 32MB f32
    unsigned short* xln  = (unsigned short*)(ws + 8388608);     // 16MB bf16
    unsigned short* x0T  = (unsigned short*)(ws + 12582912);    // 16MB bf16 [B][D][L']
    unsigned short* yT   = (unsigned short*)(ws + 16777216);    // 16MB bf16 [B][D][L]
    unsigned short* projx= (unsigned short*)(ws + 20971520);    // 32MB bf16 (x1,x2)
    unsigned short* ygp  = x0T;                                 // reuse x0T after fftconv
    unsigned short* hid  = x0T;                                 // 64MB bf16 span (x0T..projx)
    float* hT            = ws + 29360128;                       // 2MB
    float2* Hf           = (float2*)(ws + 29884416);            // 256*2056 float2
    float* part          = ws + 30937088;
    unsigned short* WTb  = (unsigned short*)(ws + 31002624);    // 4 x 786432 bf16

    for (int i = 0; i < NLAYERS; ++i) {
        unsigned short* wt = WTb + (size_t)i * 786432;
        wcastT_k<<<dim3(24, 8), 256, 0, stream>>>(in_proj_w + (size_t)i * 196608, wt, 256, 768);
        wcastT_k<<<dim3(8, 8), 256, 0, stream>>>(out_w + (size_t)i * 65536, wt + 196608, 256, 256);
        wcastT_k<<<dim3(32, 8), 256, 0, stream>>>(ffn_w1 + (size_t)i * 262144, wt + 262144, 256, 1024);
        wcastT_k<<<dim3(8, 32), 256, 0, stream>>>(ffn_w2 + (size_t)i * 262144, wt + 524288, 1024, 256);
    }

    embed_k<<<4096, 256, 0, stream>>>(x, inp_w, inp_b, xs);

    for (int i = 0; i < NLAYERS; ++i) {
        unsigned short* wt = WTb + (size_t)i * 786432;
        filt_k<<<LL, 256, 0, stream>>>(filt_w1 + i * 1024, filt_b1 + i * 64,
                                       filt_w2 + i * 16384, filt_b2 + i * 256, hT);
        ffth_k<<<DD, 256, 0, stream>>>(hT, Hf);
        lncast_k<<<8192, 256, 0, stream>>>(xs, ln1_g + i * 256, ln1_b + i * 256, xln);
        gemm_k<256, 768, 3><<<1536, 256, 0, stream>>>(
            xln, wt, in_proj_b + i * 768, x0T, projx);
        fftconv_k<<<4096, 256, 0, stream>>>(x0T, yT, Hf, short_w + i * 768, short_b + i * 256);
        gate_k<<<2048, 256, 0, stream>>>(yT, projx, ygp);
        gemm_k<256, 256, 2><<<512, 256, 0, stream>>>(
            ygp, wt + 196608, out_b + i * 256, xs, nullptr);
        lncast_k<<<8192, 256, 0, stream>>>(xs, ln2_g + i * 256, ln2_b + i * 256, xln);
        gemm_k<256, 1024, 1><<<2048, 256, 0, stream>>>(
            xln, wt + 262144, ffn_b1 + i * 1024, hid, nullptr);
        gemm_k<1024, 256, 2><<<512, 256, 0, stream>>>(
            hid, wt + 524288, ffn_b2 + i * 256, xs, nullptr);
    }

    pool_k<<<BB * 16, 256, 0, stream>>>(xs, part);
    final_k<<<BB, 256, 0, stream>>>(part, norm_g, norm_b, cls_w, cls_b, (float*)d_out);
}

// Round 6
// 788.150 us; speedup vs baseline: 5.8513x; 1.0010x over previous
//
#include <hip/hip_runtime.h>
#include <math.h>

// ---------------- model constants ----------------
#define BB 16
#define LL 2048
#define CHUNK 10
#define DD 256
#define NLAYERS 4
#define FFD 1024
#define NCLS 10
#define HSTRC 2056  // float2 stride per channel of Hf (2049 bins + pad)

typedef short bf16x8 __attribute__((ext_vector_type(8)));
typedef short s16x4 __attribute__((ext_vector_type(4)));
typedef float f32x4 __attribute__((ext_vector_type(4)));

__device__ __forceinline__ unsigned short f2bf(float f) {
    unsigned int u = __builtin_bit_cast(unsigned int, f);
    u = (u + 0x7FFF + ((u >> 16) & 1)) >> 16;
    return (unsigned short)u;
}
__device__ __forceinline__ float bf2f(unsigned short s) {
    unsigned int u = ((unsigned int)s) << 16;
    return __builtin_bit_cast(float, u);
}
__device__ __forceinline__ float bfLO(unsigned v) { return __builtin_bit_cast(float, v << 16); }
__device__ __forceinline__ float bfHI(unsigned v) { return __builtin_bit_cast(float, v & 0xFFFF0000u); }

#define PADC(a) ((a) + ((a) >> 4))

__device__ __forceinline__ float2 cmulf(float2 a, float2 b) {
    return make_float2(fmaf(-a.y, b.y, a.x * b.x), fmaf(a.y, b.x, a.x * b.y));
}

#define GLL16(gsrc, ldst) \
    __builtin_amdgcn_global_load_lds((const __attribute__((address_space(1))) void*)(gsrc), \
                                     (__attribute__((address_space(3))) void*)(ldst), 16, 0, 0)

// ================= embed =================
__global__ __launch_bounds__(256)
void embed_k(const float* __restrict__ x, const float* __restrict__ iw,
             const float* __restrict__ ib, float* __restrict__ xs)
{
    const int tid = threadIdx.x;
    const size_t row0 = (size_t)blockIdx.x * 8;
    const int i2 = (tid >> 1) * 2;
    const float div = expf(-0.03597789207803197f * (float)i2);
    float wcol[CHUNK];
#pragma unroll
    for (int c = 0; c < CHUNK; ++c) wcol[c] = iw[c * DD + tid];
    const float bv = ib[tid];
    for (int rr = 0; rr < 8; ++rr) {
        size_t row = row0 + rr;
        int l = (int)(row & (LL - 1));
        const float* xr = x + row * CHUNK;
        float acc = bv;
#pragma unroll
        for (int c = 0; c < CHUNK; ++c) acc += xr[c] * wcol[c];
        float sv, cv;
        sincosf((float)l * div, &sv, &cv);
        acc += (tid & 1) ? cv : sv;
        xs[row * DD + tid] = acc;
    }
}

// ================= filter MLP -> hT[d][l] =================
__global__ __launch_bounds__(256)
void filt_k(const float* __restrict__ fw1, const float* __restrict__ fb1,
            const float* __restrict__ fw2, const float* __restrict__ fb2,
            float* __restrict__ hT)
{
    __shared__ float pe[16];
    __shared__ float hid[64];
    const int tid = threadIdx.x, l = blockIdx.x;
    if (tid < 16) {
        int i2 = (tid >> 1) * 2;
        float div = expf(-0.5756462732485114f * (float)i2);
        float sv, cv;
        sincosf((float)l * div, &sv, &cv);
        pe[tid] = (tid & 1) ? cv : sv;
    }
    __syncthreads();
    if (tid < 64) {
        float a = fb1[tid];
#pragma unroll
        for (int e = 0; e < 16; ++e) a += pe[e] * fw1[e * 64 + tid];
        hid[tid] = 0.5f * a * (1.0f + erff(a * 0.70710678118f));
    }
    __syncthreads();
    float a = fb2[tid];
#pragma unroll
    for (int h = 0; h < 64; ++h) a += hid[h] * fw2[h * DD + tid];
    hT[(size_t)tid * LL + l] = a;
}

// ====== in-place radix-8 Stockham FFT, N=2048 = 8*8*8*4, single float2 buffer ======
__device__ __forceinline__ void dft4c(float2 a, float2 b, float2 c, float2 d,
                                      float2& F0, float2& F1, float2& F2, float2& F3)
{
    float t0r = a.x + c.x, t0i = a.y + c.y;
    float t1r = a.x - c.x, t1i = a.y - c.y;
    float t2r = b.x + d.x, t2i = b.y + d.y;
    float t3r = b.x - d.x, t3i = b.y - d.y;
    F0 = make_float2(t0r + t2r, t0i + t2i);
    F2 = make_float2(t0r - t2r, t0i - t2i);
    F1 = make_float2(t1r + t3i, t1i - t3r);   // t1 - i*t3
    F3 = make_float2(t1r - t3i, t1i + t3r);   // t1 + i*t3
}

// reads 8 (pre-barrier), twiddle-multiplies in regs, barrier, writes 8, barrier.
template <int SH>
__device__ __forceinline__ void stage8ip(float2* __restrict__ A, int tid)
{
    constexpr int ST = 1 << SH;
    const int p = tid >> SH;
    const int q = tid & (ST - 1);
    float2 x0 = A[PADC(tid)];
    float2 x1 = A[PADC(tid + 256)];
    float2 x2 = A[PADC(tid + 512)];
    float2 x3 = A[PADC(tid + 768)];
    float2 x4 = A[PADC(tid + 1024)];
    float2 x5 = A[PADC(tid + 1280)];
    float2 x6 = A[PADC(tid + 1536)];
    float2 x7 = A[PADC(tid + 1792)];
    float2 E0, E1, E2, E3, O0, O1, O2, O3;
    dft4c(x0, x2, x4, x6, E0, E1, E2, E3);
    dft4c(x1, x3, x5, x7, O0, O1, O2, O3);
    const float C8 = 0.70710678118654752f;
    float2 y0 = make_float2(E0.x + O0.x, E0.y + O0.y);
    float2 y4 = make_float2(E0.x - O0.x, E0.y - O0.y);
    float a1 = C8 * (O1.x + O1.y), b1 = C8 * (O1.y - O1.x);       // w8^1 * O1
    float2 y1 = make_float2(E1.x + a1, E1.y + b1);
    float2 y5 = make_float2(E1.x - a1, E1.y - b1);
    float2 y2 = make_float2(E2.x + O2.y, E2.y - O2.x);            // -i * O2
    float2 y6 = make_float2(E2.x - O2.y, E2.y + O2.x);
    float a3 = -C8 * (O3.x - O3.y), b3 = -C8 * (O3.x + O3.y);     // w8^3 * O3
    float2 y3 = make_float2(E3.x + a3, E3.y + b3);
    float2 y7 = make_float2(E3.x - a3, E3.y - b3);
    const int k0 = p << SH;
    float s1, c1;
    __sincosf(-3.0679615757712823e-3f * (float)k0, &s1, &c1);     // -2pi/2048 * k0
    float2 w1 = make_float2(c1, s1);
    float2 w2 = cmulf(w1, w1);
    float2 w3 = cmulf(w2, w1);
    float2 w4 = cmulf(w2, w2);
    float2 w5 = cmulf(w3, w2);
    float2 w6 = cmulf(w3, w3);
    float2 w7 = cmulf(w4, w3);
    float2 o1 = cmulf(w1, y1);
    float2 o2 = cmulf(w2, y2);
    float2 o3 = cmulf(w3, y3);
    float2 o4 = cmulf(w4, y4);
    float2 o5 = cmulf(w5, y5);
    float2 o6 = cmulf(w6, y6);
    float2 o7 = cmulf(w7, y7);
    __syncthreads();                                  // all reads complete
    const int ob = q + ((ST * p) << 3);
    A[PADC(ob)] = y0;
    A[PADC(ob + ST)] = o1;
    A[PADC(ob + 2 * ST)] = o2;
    A[PADC(ob + 3 * ST)] = o3;
    A[PADC(ob + 4 * ST)] = o4;
    A[PADC(ob + 5 * ST)] = o5;
    A[PADC(ob + 6 * ST)] = o6;
    A[PADC(ob + 7 * ST)] = o7;
    __syncthreads();                                  // all writes complete
}

// final radix-4 stage, st=512, twiddle-free (p=0), in place
__device__ __forceinline__ void stage4fip(float2* __restrict__ A, int tid)
{
    float2 v[2][4];
#pragma unroll
    for (int jj = 0; jj < 2; ++jj) {
        int u = tid + (jj << 8);
        v[jj][0] = A[PADC(u)];
        v[jj][1] = A[PADC(u + 512)];
        v[jj][2] = A[PADC(u + 1024)];
        v[jj][3] = A[PADC(u + 1536)];
    }
    __syncthreads();
#pragma unroll
    for (int jj = 0; jj < 2; ++jj) {
        int u = tid + (jj << 8);
        float2 F0, F1, F2, F3;
        dft4c(v[jj][0], v[jj][1], v[jj][2], v[jj][3], F0, F1, F2, F3);
        A[PADC(u)] = F0;
        A[PADC(u + 512)] = F1;
        A[PADC(u + 1024)] = F2;
        A[PADC(u + 1536)] = F3;
    }
    __syncthreads();
}

// full in-place FFT; caller must have a barrier between data writes and this call
__device__ __forceinline__ void fft2048ip(float2* __restrict__ A, int tid)
{
    stage8ip<0>(A, tid);
    stage8ip<3>(A, tid);
    stage8ip<6>(A, tid);
    stage4fip(A, tid);
}

// ================= Hf = rfft_4096(zero-pad(h)) per channel, interleaved =================
__global__ __launch_bounds__(256)
void ffth_k(const float* __restrict__ hT, float2* __restrict__ Hf)
{
    __shared__ float2 A2[2176];
    const int tid = threadIdx.x, d = blockIdx.x;
    const float2* rowf = reinterpret_cast<const float2*>(hT + (size_t)d * LL);
#pragma unroll
    for (int j = 0; j < 4; ++j) {
        int u = tid + (j << 8);
        A2[PADC(u)] = rowf[u];                      // z[u] = h[2u] + i h[2u+1]
        A2[PADC(u + 1024)] = make_float2(0.0f, 0.0f);
    }
    __syncthreads();
    fft2048ip(A2, tid);
    float2* hf = Hf + (size_t)d * HSTRC;
#pragma unroll
    for (int j = 0; j < 4; ++j) {
        int k = 1 + tid + (j << 8);                 // k in [1,1024]
        int m = 2048 - k;
        float2 zk = A2[PADC(k)], zm = A2[PADC(m)];
        float Er = 0.5f * (zk.x + zm.x), Ei = 0.5f * (zk.y - zm.y);
        float Or = 0.5f * (zk.y + zm.y), Oi = -0.5f * (zk.x - zm.x);
        float ts, tc;
        __sincosf(-1.5339807878856412e-3f * (float)k, &ts, &tc);  // -2pi/4096 * k
        float TOr = tc * Or - ts * Oi, TOi = tc * Oi + ts * Or;
        hf[k] = make_float2(Er + TOr, Ei + TOi);                  // H[k]
        hf[m] = make_float2(Er - TOr, -(Ei - TOi));               // H[2048-k]
    }
    if (tid == 0) {
        float2 z0 = A2[PADC(0)];
        hf[0] = make_float2(z0.x + z0.y, z0.x - z0.y);            // (H[0], H[2048])
    }
}

// ====== fused conv3 + fft conv (single-buffer in-place): x0T(bf16) -> yT(bf16) ======
__global__ __launch_bounds__(256, 4)
void fftconv_k(const unsigned short* __restrict__ x0T, unsigned short* __restrict__ yT,
               const float2* __restrict__ Hf, const float* __restrict__ sw,
               const float* __restrict__ sb)
{
    __shared__ float2 A2[2176];
    const int tid = threadIdx.x;
    // XCD-locality swizzle: XCD c handles channels d in [32c, 32c+32), all b
    const int w = blockIdx.x;
    const int c = w & 7, s = w >> 3;
    const int d = c * 32 + (s & 31);
    const int b = s >> 5;
    const int blk = b * 256 + d;
    const float w0 = sw[d * 3], w1 = sw[d * 3 + 1], w2 = sw[d * 3 + 2];
    const float bv = sb[d];

    // ---- load bf16 row (field-swap permuted within 64-blocks) into LDS floats ----
    float* rawF = reinterpret_cast<float*>(A2);      // first 8 KB of A2
    {
        const uint4* rowv = reinterpret_cast<const uint4*>(x0T + (size_t)blk * LL);
        uint4 ld = rowv[tid];
        int p = tid << 3;                 // stored position of first bf16
        int lB = p & ~63;
        int p6 = p & 63;
        int fg = p6 >> 4;
        int m0 = (p6 >> 2) & 3;           // in {0, 2}
        float4* d0 = reinterpret_cast<float4*>(rawF + lB + m0 * 16 + fg * 4);
        float4* d1 = reinterpret_cast<float4*>(rawF + lB + (m0 + 1) * 16 + fg * 4);
        *d0 = make_float4(bfLO(ld.x), bfHI(ld.x), bfLO(ld.y), bfHI(ld.y));
        *d1 = make_float4(bfLO(ld.z), bfHI(ld.z), bfLO(ld.w), bfHI(ld.w));
    }
    __syncthreads();
    // ---- depthwise conv3 + complex pack into regs (reads all before overlay write) ----
    float2 zv[4];
#pragma unroll
    for (int j = 0; j < 4; ++j) {
        int u = tid + (j << 8);
        float xm1 = (u == 0) ? 0.0f : rawF[2 * u - 1];
        float xc0 = rawF[2 * u];
        float xp1 = rawF[2 * u + 1];
        float xp2 = (u == 1023) ? 0.0f : rawF[2 * u + 2];
        zv[j].x = bv + w0 * xm1 + w1 * xc0 + w2 * xp1;
        zv[j].y = bv + w0 * xc0 + w1 * xp1 + w2 * xp2;
    }
    __syncthreads();
#pragma unroll
    for (int j = 0; j < 4; ++j) {
        int u = tid + (j << 8);
        A2[PADC(u)] = zv[j];
        A2[PADC(u + 1024)] = make_float2(0.0f, 0.0f);
    }
    __syncthreads();
    fft2048ip(A2, tid);                             // Z in A2
    // ---- untangle, multiply by H, retangle (thread-local disjoint pairs; no barrier) ----
    const float2* hf = Hf + (size_t)d * HSTRC;
#pragma unroll
    for (int j = 0; j < 4; ++j) {
        int k = 1 + tid + (j << 8);
        int m = 2048 - k;
        float2 zk = A2[PADC(k)], zm = A2[PADC(m)];
        float Er = 0.5f * (zk.x + zm.x), Ei = 0.5f * (zk.y - zm.y);
        float Or = 0.5f * (zk.y + zm.y), Oi = -0.5f * (zk.x - zm.x);
        float ts, tc;
        __sincosf(-1.5339807878856412e-3f * (float)k, &ts, &tc);
        float TOr = tc * Or - ts * Oi, TOi = tc * Oi + ts * Or;
        float Xpr = Er + TOr, Xpi = Ei + TOi;       // X[k]
        float Xmr = Er - TOr, Xmi = Ei - TOi;       // conj(X[m])
        float2 hk = hf[k], hm = hf[m];
        float Ykr = Xpr * hk.x - Xpi * hk.y, Yki = Xpr * hk.y + Xpi * hk.x;
        float Cr = Xmr * hm.x + Xmi * hm.y, Ci = Xmi * hm.x - Xmr * hm.y;
        float Pr = 0.5f * (Ykr + Cr), Pi = 0.5f * (Yki + Ci);
        float Gr = 0.5f * (Ykr - Cr), Gi = 0.5f * (Yki - Ci);
        float Qr = tc * Gr + ts * Gi, Qi = tc * Gi - ts * Gr;
        A2[PADC(k)] = make_float2(Pr - Qi, -(Pi + Qr));
        A2[PADC(m)] = make_float2(Pr + Qi, Pi - Qr);
    }
    if (tid == 0) {
        float2 z0 = A2[PADC(0)];
        float2 h0 = hf[0];
        float X0 = z0.x + z0.y, X2 = z0.x - z0.y;
        float Y0 = X0 * h0.x, Y2 = X2 * h0.y;
        float P = 0.5f * (Y0 + Y2), Q = 0.5f * (Y0 - Y2);
        A2[PADC(0)] = make_float2(P, -Q);
    }
    __syncthreads();
    fft2048ip(A2, tid);                             // FFT of conj(W)
    const float sc = 1.0f / 2048.0f;
    unsigned* yrow = reinterpret_cast<unsigned*>(yT + (size_t)blk * LL);
#pragma unroll
    for (int j = 0; j < 4; ++j) {
        int u = tid + (j << 8);
        float2 v = A2[PADC(u)];
        float e = v.x * sc, o = -v.y * sc;
        yrow[u] = (unsigned)f2bf(e) | ((unsigned)f2bf(o) << 16);
    }
}

// ================= gate + transpose: yg(B,L,D) bf16 = yT * x1 * x2 =================
__global__ __launch_bounds__(256)
void gate_k(const unsigned short* __restrict__ yTb, const unsigned short* __restrict__ px,
            unsigned short* __restrict__ yg)
{
    __shared__ float t[64][65];
    const int tid = threadIdx.x;
    const int blk = blockIdx.x;
    const int b = blk >> 7;
    const int dt = (blk >> 5) & 3;
    const int lt = blk & 31;
    const int d0 = dt << 6, l0 = lt << 6;
    const int r0 = tid >> 6, c = tid & 63;
    for (int rr = 0; rr < 16; ++rr) {
        int dl = rr * 4 + r0;
        t[dl][c] = bf2f(yTb[(((size_t)(b << 8) + d0 + dl) << 11) + l0 + c]);
    }
    __syncthreads();
    const int lid = tid & 63, lr = tid >> 6;
    for (int k = 0; k < 16; ++k) {
        int ll = k * 4 + lr;
        int l = l0 + ll;
        size_t pb = ((size_t)(b * LL + l)) * 512;
        float v = t[lid][ll];
        float x1 = bf2f(px[pb + d0 + lid]);
        float x2 = bf2f(px[pb + 256 + d0 + lid]);
        yg[((size_t)(b * LL + l)) * DD + d0 + lid] = f2bf(v * x1 * x2);
    }
}

// ================= LN + cast to bf16 (only after embed) =================
__global__ __launch_bounds__(256)
void lncast_k(const float* __restrict__ xs, const float* __restrict__ g,
              const float* __restrict__ b, unsigned short* __restrict__ o)
{
    const int tid = threadIdx.x, lane = tid & 63, wave = tid >> 6;
    const size_t row = (size_t)blockIdx.x * 4 + wave;
    float4 v = reinterpret_cast<const float4*>(xs + row * DD)[lane];
    float s = v.x + v.y + v.z + v.w;
#pragma unroll
    for (int off = 32; off > 0; off >>= 1) s += __shfl_xor(s, off, 64);
    float mean = s * (1.0f / 256.0f);
    float e0 = v.x - mean, e1 = v.y - mean, e2 = v.z - mean, e3 = v.w - mean;
    float q = e0 * e0 + e1 * e1 + e2 * e2 + e3 * e3;
#pragma unroll
    for (int off = 32; off > 0; off >>= 1) q += __shfl_xor(q, off, 64);
    float rstd = rsqrtf(q * (1.0f / 256.0f) + 1e-5f);
    float4 gg = reinterpret_cast<const float4*>(g)[lane];
    float4 bb = reinterpret_cast<const float4*>(b)[lane];
    s16x4 r;
    r[0] = (short)f2bf(e0 * rstd * gg.x + bb.x);
    r[1] = (short)f2bf(e1 * rstd * gg.y + bb.y);
    r[2] = (short)f2bf(e2 * rstd * gg.z + bb.z);
    r[3] = (short)f2bf(e3 * rstd * gg.w + bb.w);
    *reinterpret_cast<s16x4*>(o + row * DD + lane * 4) = r;
}

// ================= weight cast + transpose =================
__global__ __launch_bounds__(256)
void wcastT_k(const float* __restrict__ W, unsigned short* __restrict__ WT, int K, int N)
{
    __shared__ float t[32][33];
    const int tx = threadIdx.x & 31, ty = threadIdx.x >> 5;
    const int n0 = blockIdx.x * 32, k0 = blockIdx.y * 32;
#pragma unroll
    for (int j = 0; j < 4; ++j)
        t[ty + 8 * j][tx] = W[(size_t)(k0 + ty + 8 * j) * N + n0 + tx];
    __syncthreads();
#pragma unroll
    for (int j = 0; j < 4; ++j)
        WT[(size_t)(n0 + ty + 8 * j) * K + k0 + tx] = f2bf(t[tx][ty + 8 * j]);
}

// ================= bf16 MFMA GEMM (generic) =================
// MODE 1: GELU -> bf16. MODE 2: += into f32. MODE 3: x0 transposed(field-swap) + x1x2.
template <int K, int N, int MODE>
__global__ __launch_bounds__(256)
void gemm_k(const unsigned short* __restrict__ A, const unsigned short* __restrict__ WT,
            const float* __restrict__ bias, void* __restrict__ outp, void* __restrict__ outp2)
{
    constexpr int C = N / 128;
    __shared__ unsigned short ldsA[8192];
    __shared__ unsigned short ldsB[8192];
    const int tid = threadIdx.x;
    const int lane = tid & 63, wid = tid >> 6;
    const int nwg = gridDim.x;
    const int w = blockIdx.x;
    const int logical = (w & 7) * (nwg >> 3) + (w >> 3);
    const int row0 = (logical / C) * 128;
    const int col0 = (logical % C) * 128;
    const int wm = (wid >> 1) * 64, wn = (wid & 1) * 64;
    const int fr = lane & 15, fg = lane >> 4;

    f32x4 acc[4][4];
#pragma unroll
    for (int n = 0; n < 4; ++n) {
        float bv = bias[col0 + wn + n * 16 + fr];
#pragma unroll
        for (int m = 0; m < 4; ++m) {
            acc[m][n][0] = bv; acc[m][n][1] = bv; acc[m][n][2] = bv; acc[m][n][3] = bv;
        }
    }

    const int srow = wid * 8 + (lane >> 3);
    const int sc = lane & 7;

    for (int kt = 0; kt < K / 64; ++kt) {
        const int k0 = kt * 64;
#pragma unroll
        for (int it = 0; it < 4; ++it) {
            int row = it * 32 + srow;
            int cs = sc ^ (row & 7);
            const char* ga = (const char*)(A + (size_t)(row0 + row) * K + k0) + cs * 16;
            const char* gb = (const char*)(WT + (size_t)(col0 + row) * K + k0) + cs * 16;
            GLL16(ga, (char*)ldsA + it * 4096 + wid * 1024);
            GLL16(gb, (char*)ldsB + it * 4096 + wid * 1024);
        }
        __syncthreads();
#pragma unroll
        for (int ks = 0; ks < 2; ++ks) {
            bf16x8 af[4], bf[4];
#pragma unroll
            for (int m = 0; m < 4; ++m) {
                int ar = wm + m * 16 + fr;
                int slot = (ks * 4 + fg) ^ (ar & 7);
                af[m] = *reinterpret_cast<const bf16x8*>(ldsA + ar * 64 + slot * 8);
            }
#pragma unroll
            for (int n = 0; n < 4; ++n) {
                int br = wn + n * 16 + fr;
                int slot = (ks * 4 + fg) ^ (br & 7);
                bf[n] = *reinterpret_cast<const bf16x8*>(ldsB + br * 64 + slot * 8);
            }
#pragma unroll
            for (int m = 0; m < 4; ++m)
#pragma unroll
                for (int n = 0; n < 4; ++n)
                    acc[m][n] = __builtin_amdgcn_mfma_f32_16x16x32_bf16(af[m], bf[n], acc[m][n], 0, 0, 0);
        }
        __syncthreads();
    }

    if constexpr (MODE == 3) {
        if (col0 < 256) {
            // x0: transposed bf16 [b][d][l'], field-swap within each 64-l block.
            const int b = row0 >> 11;
            const int lb0 = (row0 & (LL - 1)) + wm;
#pragma unroll
            for (int n = 0; n < 4; ++n) {
                int dcol = col0 + wn + n * 16 + fr;
                unsigned short* dst = (unsigned short*)outp +
                    (((size_t)(b << 8) + dcol) << 11) + lb0 + fg * 16;
                unsigned pk[8];
#pragma unroll
                for (int q = 0; q < 8; ++q) {
                    int m = q >> 1, r0 = (q & 1) * 2;
                    pk[q] = (unsigned)f2bf(acc[m][n][r0]) | ((unsigned)f2bf(acc[m][n][r0 + 1]) << 16);
                }
                *reinterpret_cast<uint4*>(dst)     = make_uint4(pk[0], pk[1], pk[2], pk[3]);
                *reinterpret_cast<uint4*>(dst + 8) = make_uint4(pk[4], pk[5], pk[6], pk[7]);
            }
        } else {
            unsigned short* px = (unsigned short*)outp2;
#pragma unroll
            for (int m = 0; m < 4; ++m) {
                int gr = row0 + wm + m * 16 + fg * 4;
#pragma unroll
                for (int n = 0; n < 4; ++n) {
                    int gc = col0 - 256 + wn + n * 16 + fr;
#pragma unroll
                    for (int r = 0; r < 4; ++r)
                        px[(size_t)(gr + r) * 512 + gc] = f2bf(acc[m][n][r]);
                }
            }
        }
        return;
    }

#pragma unroll
    for (int m = 0; m < 4; ++m) {
        int gr = row0 + wm + m * 16 + fg * 4;
#pragma unroll
        for (int n = 0; n < 4; ++n) {
            int gc = col0 + wn + n * 16 + fr;
#pragma unroll
            for (int r = 0; r < 4; ++r) {
                float v = acc[m][n][r];
                if constexpr (MODE == 1) v = 0.5f * v * (1.0f + erff(v * 0.70710678118f));
                if constexpr (MODE <= 1) {
                    ((unsigned short*)outp)[(size_t)(gr + r) * N + gc] = f2bf(v);
                } else {
                    float* o = (float*)outp + (size_t)(gr + r) * N + gc;
                    *o += v;
                }
            }
        }
    }
}

// ====== fused GEMM(N=256) + residual + LayerNorm + bf16 cast ======
// Block: 64 rows x 256 cols. Wave = 16 rows x 256 cols (acc[16] f32x4).
// xs (f32) gets += gemm_out; xln (bf16) gets LN(xs_new).
template <int K>
__global__ __launch_bounds__(256)
void gemm_ln_k(const unsigned short* __restrict__ A, const unsigned short* __restrict__ WT,
               const float* __restrict__ bias, const float* __restrict__ lng,
               const float* __restrict__ lnb, float* __restrict__ xs,
               unsigned short* __restrict__ xln)
{
    __shared__ unsigned short ldsA[64 * 64];    // 8 KB
    __shared__ unsigned short ldsB[256 * 64];   // 32 KB
    const int tid = threadIdx.x;
    const int lane = tid & 63, wid = tid >> 6;
    const int nwg = gridDim.x;   // 512
    const int w = blockIdx.x;
    const int logical = (w & 7) * (nwg >> 3) + (w >> 3);
    const size_t row0 = (size_t)logical * 64;
    const int fr = lane & 15, fg = lane >> 4;

    f32x4 acc[16];
#pragma unroll
    for (int n = 0; n < 16; ++n) {
        float bv = bias[n * 16 + fr];
        acc[n][0] = bv; acc[n][1] = bv; acc[n][2] = bv; acc[n][3] = bv;
    }

    for (int kt = 0; kt < K / 64; ++kt) {
        const int k0 = kt * 64;
#pragma unroll
        for (int p = 0; p < 2; ++p) {
            int cch = p * 256 + tid;
            int row = cch >> 3;
            int cs = (cch & 7) ^ (row & 7);
            const char* ga = (const char*)(A + (row0 + row) * K + k0) + cs * 16;
            GLL16(ga, (char*)ldsA + p * 4096 + wid * 1024);
        }
#pragma unroll
        for (int p = 0; p < 8; ++p) {
            int cch = p * 256 + tid;
            int row = cch >> 3;
            int cs = (cch & 7) ^ (row & 7);
            const char* gb = (const char*)(WT + (size_t)row * K + k0) + cs * 16;
            GLL16(gb, (char*)ldsB + p * 4096 + wid * 1024);
        }
        __syncthreads();
#pragma unroll
        for (int ks = 0; ks < 2; ++ks) {
            int ar = wid * 16 + fr;
            int slotA = (ks * 4 + fg) ^ (ar & 7);
            bf16x8 af = *reinterpret_cast<const bf16x8*>(ldsA + ar * 64 + slotA * 8);
#pragma unroll
            for (int n = 0; n < 16; ++n) {
                int br = n * 16 + fr;
                int slotB = (ks * 4 + fg) ^ (br & 7);
                bf16x8 bf = *reinterpret_cast<const bf16x8*>(ldsB + br * 64 + slotB * 8);
                acc[n] = __builtin_amdgcn_mfma_f32_16x16x32_bf16(af, bf, acc[n], 0, 0, 0);
            }
        }
        __syncthreads();
    }

    // ---- epilogue: residual add, per-row LN over 256 cols, write xs + xln ----
    const size_t rbase = row0 + wid * 16 + fg * 4;   // +r gives the row
#pragma unroll
    for (int r = 0; r < 4; ++r) {
        const float* xr = xs + (rbase + r) * DD;
#pragma unroll
        for (int n = 0; n < 16; ++n)
            acc[n][r] += xr[fr + 16 * n];
    }
    float sm[4], sq[4];
#pragma unroll
    for (int r = 0; r < 4; ++r) {
        float s = 0.0f, q = 0.0f;
#pragma unroll
        for (int n = 0; n < 16; ++n) {
            float v = acc[n][r];
            s += v; q += v * v;
        }
#pragma unroll
        for (int off = 1; off < 16; off <<= 1) {
            s += __shfl_xor(s, off, 64);
            q += __shfl_xor(q, off, 64);
        }
        sm[r] = s * (1.0f / 256.0f);
        float var = q * (1.0f / 256.0f) - sm[r] * sm[r];
        sq[r] = rsqrtf(var + 1e-5f);
    }
    float gv[16], bvv[16];
#pragma unroll
    for (int n = 0; n < 16; ++n) {
        gv[n] = lng[fr + 16 * n];
        bvv[n] = lnb[fr + 16 * n];
    }
#pragma unroll
    for (int r = 0; r < 4; ++r) {
        float* xw = xs + (rbase + r) * DD;
        unsigned short* lw = xln + (rbase + r) * DD;
#pragma unroll
        for (int n = 0; n < 16; ++n) {
            int gc = fr + 16 * n;
            float v = acc[n][r];
            xw[gc] = v;
            lw[gc] = f2bf((v - sm[r]) * sq[r] * gv[n] + bvv[n]);
        }
    }
}

// ================= mean pool (partial) =================
__global__ __launch_bounds__(256)
void pool_k(const float* __restrict__ xs, float* __restrict__ part)
{
    const int tid = threadIdx.x;
    const int b = blockIdx.x >> 4, g = blockIdx.x & 15;
    size_t base = ((size_t)b * LL + g * 128) * DD + tid;
    float s = 0.0f;
    for (int l = 0; l < 128; ++l) s += xs[base + (size_t)l * DD];
    part[(size_t)blockIdx.x * DD + tid] = s;
}

// ================= final =================
__global__ __launch_bounds__(256)
void final_k(const float* __restrict__ part, const float* __restrict__ ng,
             const float* __restrict__ nb, const float* __restrict__ cw,
             const float* __restrict__ cb, float* __restrict__ out)
{
    __shared__ float pl[256];
    __shared__ float red[4], red2[4];
    const int tid = threadIdx.x, b = blockIdx.x;
    float m = 0.0f;
    for (int g = 0; g < 16; ++g) m += part[((size_t)b * 16 + g) * DD + tid];
    m *= (1.0f / (float)LL);
    const int lane = tid & 63, wave = tid >> 6;
    float s = m;
#pragma unroll
    for (int off = 32; off > 0; off >>= 1) s += __shfl_xor(s, off, 64);
    if (lane == 0) red[wave] = s;
    __syncthreads();
    float mean = (red[0] + red[1] + red[2] + red[3]) * (1.0f / 256.0f);
    float dm = m - mean;
    float qv = dm * dm;
#pragma unroll
    for (int off = 32; off > 0; off >>= 1) qv += __shfl_xor(qv, off, 64);
    if (lane == 0) red2[wave] = qv;
    __syncthreads();
    float var = (red2[0] + red2[1] + red2[2] + red2[3]) * (1.0f / 256.0f);
    pl[tid] = dm * rsqrtf(var + 1e-5f) * ng[tid] + nb[tid];
    __syncthreads();
    if (tid < NCLS) {
        float a = cb[tid];
        for (int dd = 0; dd < 256; ++dd) a += pl[dd] * cw[dd * NCLS + tid];
        out[b * NCLS + tid] = a;
    }
}

// ================= launcher =================
extern "C" void kernel_launch(void* const* d_in, const int* in_sizes, int n_in,
                              void* d_out, int out_size, void* d_ws, size_t ws_size,
                              hipStream_t stream)
{
    (void)in_sizes; (void)n_in; (void)out_size; (void)ws_size;
    const float* x        = (const float*)d_in[0];
    const float* inp_w    = (const float*)d_in[1];
    const float* inp_b    = (const float*)d_in[2];
    const float* in_proj_w= (const float*)d_in[3];
    const float* in_proj_b= (const float*)d_in[4];
    const float* short_w  = (const float*)d_in[5];
    const float* short_b  = (const float*)d_in[6];
    const float* filt_w1  = (const float*)d_in[7];
    const float* filt_b1  = (const float*)d_in[8];
    const float* filt_w2  = (const float*)d_in[9];
    const float* filt_b2  = (const float*)d_in[10];
    const float* out_w    = (const float*)d_in[11];
    const float* out_b    = (const float*)d_in[12];
    const float* ln1_g    = (const float*)d_in[13];
    const float* ln1_b    = (const float*)d_in[14];
    const float* ln2_g    = (const float*)d_in[15];
    const float* ln2_b    = (const float*)d_in[16];
    const float* ffn_w1   = (const float*)d_in[17];
    const float* ffn_b1   = (const float*)d_in[18];
    const float* ffn_w2   = (const float*)d_in[19];
    const float* ffn_b2   = (const float*)d_in[20];
    const float* norm_g   = (const float*)d_in[21];
    const float* norm_b   = (const float*)d_in[22];
    const float* cls_w    = (const float*)d_in[23];
    const float* cls_b    = (const float*)d_in[24];

    float* ws = (float*)d_ws;
    float* xs            = ws;                                  // 32MB f32
    unsigned short* xln  = (unsigned short*)(ws + 8388608);     // 16MB bf16
    unsigned short* x0T  = (unsigned short*)(ws + 12582912);    // 16MB bf16 [B][D][L']
    unsigned short* yT   = (unsigned short*)(ws + 16777216);    // 16MB bf16 [B][D][L]
    unsigned short* projx= (unsigned short*)(ws + 20971520);    // 32MB bf16 (x1,x2)
    unsigned short* ygp  = x0T;                                 // reuse x0T after fftconv
    unsigned short* hid  = x0T;                                 // 64MB bf16 span (x0T..projx)
    float* hT            = ws + 29360128;                       // 2MB
    float2* Hf           = (float2*)(ws + 29884416);            // 256*2056 float2
    float* part          = ws + 30937088;
    unsigned short* WTb  = (unsigned short*)(ws + 31002624);    // 4 x 786432 bf16

    for (int i = 0; i < NLAYERS; ++i) {
        unsigned short* wt = WTb + (size_t)i * 786432;
        wcastT_k<<<dim3(24, 8), 256, 0, stream>>>(in_proj_w + (size_t)i * 196608, wt, 256, 768);
        wcastT_k<<<dim3(8, 8), 256, 0, stream>>>(out_w + (size_t)i * 65536, wt + 196608, 256, 256);
        wcastT_k<<<dim3(32, 8), 256, 0, stream>>>(ffn_w1 + (size_t)i * 262144, wt + 262144, 256, 1024);
        wcastT_k<<<dim3(8, 32), 256, 0, stream>>>(ffn_w2 + (size_t)i * 262144, wt + 524288, 1024, 256);
    }

    embed_k<<<4096, 256, 0, stream>>>(x, inp_w, inp_b, xs);
    lncast_k<<<8192, 256, 0, stream>>>(xs, ln1_g, ln1_b, xln);   // LN1 of layer 0

    for (int i = 0; i < NLAYERS; ++i) {
        unsigned short* wt = WTb + (size_t)i * 786432;
        filt_k<<<LL, 256, 0, stream>>>(filt_w1 + i * 1024, filt_b1 + i * 64,
                                       filt_w2 + i * 16384, filt_b2 + i * 256, hT);
        ffth_k<<<DD, 256, 0, stream>>>(hT, Hf);
        gemm_k<256, 768, 3><<<1536, 256, 0, stream>>>(
            xln, wt, in_proj_b + i * 768, x0T, projx);
        fftconv_k<<<4096, 256, 0, stream>>>(x0T, yT, Hf, short_w + i * 768, short_b + i * 256);
        gate_k<<<2048, 256, 0, stream>>>(yT, projx, ygp);
        // out-proj: xs += ygp @ ow + ob ; xln = LN2(xs)
        gemm_ln_k<256><<<512, 256, 0, stream>>>(
            ygp, wt + 196608, out_b + i * 256, ln2_g + i * 256, ln2_b + i * 256, xs, xln);
        gemm_k<256, 1024, 1><<<2048, 256, 0, stream>>>(
            xln, wt + 262144, ffn_b1 + i * 1024, hid, nullptr);
        if (i < NLAYERS - 1) {
            // ffn2: xs += hid @ w2 + b2 ; xln = LN1[i+1](xs)
            gemm_ln_k<1024><<<512, 256, 0, stream>>>(
                hid, wt + 524288, ffn_b2 + i * 256,
                ln1_g + (i + 1) * 256, ln1_b + (i + 1) * 256, xs, xln);
        } else {
            gemm_k<1024, 256, 2><<<512, 256, 0, stream>>>(
                hid, wt + 524288, ffn_b2 + i * 256, xs, nullptr);
        }
    }

    pool_k<<<BB * 16, 256, 0, stream>>>(xs, part);
    final_k<<<BB, 256, 0, stream>>>(part, norm_g, norm_b, cls_w, cls_b, (float*)d_out);
}